// Round 10
// baseline (432.589 us; speedup 1.0000x reference)
//
#include <hip/hip_runtime.h>
#include <math.h>

#define NPT   8192
#define FIN   256
#define DD    64
#define KSEL  48
#define SSEG  320

#define LEAKY(x) (((x) >= 0.f) ? (x) : 0.01f*(x))

using short8v = __attribute__((ext_vector_type(8))) short;
using f32x4   = __attribute__((ext_vector_type(4))) float;

__device__ inline unsigned short f2bf(float x) {
  union { float f; unsigned u; } v; v.f = x;
  unsigned r = v.u + 0x7fff + ((v.u >> 16) & 1);   // RNE
  return (unsigned short)(r >> 16);
}
__device__ inline float bf2f(unsigned short h) {
  union { unsigned u; float f; } v; v.u = ((unsigned)h) << 16; return v.f;
}
__device__ inline unsigned key_of(float f) {
  unsigned u = __float_as_uint(f);
  return (u & 0x80000000u) ? ~u : (u | 0x80000000u);
}
__device__ inline float key_inv(unsigned k) {
  unsigned u = (k >> 31) ? (k ^ 0x80000000u) : ~k;
  return __uint_as_float(u);
}

// ---------------- K0: transposes ----------------
__global__ void k0_prep(const float* __restrict__ Wl, const float* __restrict__ Wb,
                        const float* __restrict__ Wt1, const float* __restrict__ Wp1,
                        const float* __restrict__ Wt2, const float* __restrict__ Wp2,
                        float* __restrict__ WlT, float* __restrict__ WbT,
                        float* __restrict__ WtT1, float* __restrict__ WpT1,
                        float* __restrict__ WtT2, float* __restrict__ WpT2)
{
  const int b = blockIdx.x, t = threadIdx.x;
  if (b < 192) {
    WlT[b*256 + t] = Wl[t*192 + b];
  } else if (b < 256) {
    int j = (b - 192)*4 + (t >> 6), o = t & 63;
    WbT[j*64 + o] = Wb[o*256 + j];
  } else {
    int m = b - 256;
    const float* src = (m==0) ? Wt1 : (m==1) ? Wp1 : (m==2) ? Wt2 : Wp2;
    float*       dst = (m==0) ? WtT1: (m==1) ? WpT1: (m==2) ? WtT2: WpT2;
    #pragma unroll
    for (int i = 0; i < 16; ++i) {
      int idx = t + 256*i, r = idx >> 6, c = idx & 63;
      dst[c*64 + r] = src[r*64 + c];
    }
  }
}

// ---------------- K1: per-node precompute (4-acc fp64 ILP) ----------------
__global__ __launch_bounds__(256) void k1_precompute(
    const float* __restrict__ feature, const float* __restrict__ WbT, const float* __restrict__ bb,
    const float* __restrict__ WtT1, const float* __restrict__ bt1,
    const float* __restrict__ WpT1, const float* __restrict__ bp1,
    const float* __restrict__ WtT2, const float* __restrict__ bt2,
    const float* __restrict__ WpT2, const float* __restrict__ bp2,
    double* __restrict__ f64d, double* __restrict__ sq64,
    float* __restrict__ f32v, float* __restrict__ sqf,
    float* __restrict__ u1, float* __restrict__ c1,
    float* __restrict__ u2, float* __restrict__ c2)
{
  __shared__ float f_s[4*64];
  const int w = threadIdx.x >> 6, l = threadIdx.x & 63;
  const int i = blockIdx.x*4 + w;
  const float* frow = feature + i*FIN;
  double a0 = (double)bb[l], a1 = 0.0, a2 = 0.0, a3 = 0.0;
  #pragma unroll 2
  for (int j = 0; j < FIN; j += 4) {
    float4 fv = *(const float4*)&frow[j];
    a0 += (double)fv.x * (double)WbT[(j+0)*64 + l];
    a1 += (double)fv.y * (double)WbT[(j+1)*64 + l];
    a2 += (double)fv.z * (double)WbT[(j+2)*64 + l];
    a3 += (double)fv.w * (double)WbT[(j+3)*64 + l];
  }
  double facc = (a0 + a1) + (a2 + a3);
  f64d[i*DD + l] = facc;
  float f32 = (float)facc;
  f32v[i*DD + l] = f32;
  double s = facc*facc;
  #pragma unroll
  for (int off = 32; off; off >>= 1) s += __shfl_xor(s, off);
  if (l == 0) { sq64[i] = s; sqf[i] = (float)s; }
  f_s[w*64 + l] = f32;
  float au1 = 0.f, ap1 = 0.f, au2 = 0.f, ap2 = 0.f;
  for (int e = 0; e < DD; ++e) {
    float fe = f_s[w*64 + e];
    au1 += fe * WtT1[e*64 + l];
    ap1 += fe * WpT1[e*64 + l];
    au2 += fe * WtT2[e*64 + l];
    ap2 += fe * WpT2[e*64 + l];
  }
  u1[i*DD+l] = au1;
  c1[i*DD+l] = ap1 + bp1[l] + au1 + bt1[l];
  u2[i*DD+l] = au2;
  c2[i*DD+l] = ap2 + bp2[l] + au2 + bt2[l];
}

// ---------------- K1b: MFMA fragments for KNN (bf16 hi/lo) ----------------
__global__ __launch_bounds__(256) void k1b_frag(
    const float* __restrict__ f32v,
    unsigned short* __restrict__ Saf, unsigned short* __restrict__ Sbf)
{
  const int w = threadIdx.x >> 6, l = threadIdx.x & 63;
  const int task = blockIdx.x*4 + w;          // 0..3071
  const int tile = task / 6, ks = task % 6;
  const int row  = tile*16 + (l & 15);
  const int inner = (ks & 1)*32 + ((l >> 4) << 3);
  union { unsigned short u[8]; short8v v; } pa, pb;
  #pragma unroll
  for (int j = 0; j < 8; ++j) {
    float x = f32v[row*64 + inner + j];
    unsigned short hi = f2bf(x);
    unsigned short lo = f2bf(x - bf2f(hi));
    pa.u[j] = (ks < 4) ? hi : lo;
    pb.u[j] = (ks < 2) ? hi : ((ks < 4) ? lo : hi);
  }
  size_t off = ((size_t)(tile*6 + ks)*64 + l)*8;
  *(short8v*)&Saf[off] = pa.v;
  *(short8v*)&Sbf[off] = pb.v;
}

// ---------------- K1c: weight B-fragments for edge-conv MLPs ----------------
__global__ __launch_bounds__(256) void k1c_wfrag(
    const float* __restrict__ Wm1a, const float* __restrict__ Wm1b,
    const float* __restrict__ Wm2a, const float* __restrict__ Wm2b,
    unsigned short* __restrict__ F1a, unsigned short* __restrict__ F1b,
    unsigned short* __restrict__ F2a, unsigned short* __restrict__ F2b)
{
  const int w = threadIdx.x >> 6, l = threadIdx.x & 63;
  const int task = blockIdx.x*4 + w;          // 0..95
  const int which = task / 24, rem = task % 24;
  const int nt = rem / 6, ks = rem % 6;
  const float* W = (which==0) ? Wm1a : (which==1) ? Wm1b : (which==2) ? Wm2a : Wm2b;
  unsigned short* F = (which==0) ? F1a : (which==1) ? F1b : (which==2) ? F2a : F2b;
  const int row = nt*16 + (l & 15);
  const int inner = (ks & 1)*32 + ((l >> 4) << 3);
  union { unsigned short u[8]; short8v v; } p;
  #pragma unroll
  for (int j = 0; j < 8; ++j) {
    float x = W[row*64 + inner + j];
    unsigned short hi = f2bf(x);
    unsigned short lo = f2bf(x - bf2f(hi));
    p.u[j] = (ks < 2) ? hi : ((ks < 4) ? lo : hi);
  }
  *(short8v*)&F[((size_t)(nt*6 + ks)*64 + l)*8] = p.v;
}

#define MFMA_PAIR6(ACC, AF, BF)                                                  \
  ACC = __builtin_amdgcn_mfma_f32_16x16x32_bf16(AF[0], BF[0], ACC, 0, 0, 0);     \
  ACC = __builtin_amdgcn_mfma_f32_16x16x32_bf16(AF[1], BF[1], ACC, 0, 0, 0);     \
  ACC = __builtin_amdgcn_mfma_f32_16x16x32_bf16(AF[0], BF[2], ACC, 0, 0, 0);     \
  ACC = __builtin_amdgcn_mfma_f32_16x16x32_bf16(AF[1], BF[3], ACC, 0, 0, 0);     \
  ACC = __builtin_amdgcn_mfma_f32_16x16x32_bf16(AF[2], BF[0], ACC, 0, 0, 0);     \
  ACC = __builtin_amdgcn_mfma_f32_16x16x32_bf16(AF[3], BF[1], ACC, 0, 0, 0);

// ---------------- K2a: sampled distances (8 of 64 chunks), grid 512 ----------------
__global__ __launch_bounds__(512) void k2a_sample(
    const unsigned short* __restrict__ Saf,
    const unsigned short* __restrict__ Sbf,
    const float* __restrict__ sqf,
    float* __restrict__ sampD)
{
  const int t = threadIdx.x, w = t >> 6, l = t & 63;
  const int qb = blockIdx.x >> 1, sh = blockIdx.x & 1;
  const int qbase = qb * 32;
  short8v afr[2][4];
  #pragma unroll
  for (int mt = 0; mt < 2; ++mt) {
    const size_t b = (size_t)(qb*2 + mt)*6;
    afr[mt][0] = *(const short8v*)&Saf[((b+0)*64 + l)*8];
    afr[mt][1] = *(const short8v*)&Saf[((b+1)*64 + l)*8];
    afr[mt][2] = *(const short8v*)&Saf[((b+4)*64 + l)*8];
    afr[mt][3] = *(const short8v*)&Saf[((b+5)*64 + l)*8];
  }
  const int ncol = w*16 + (l & 15);
  for (int sl = 0; sl < 4; ++sl) {
    const int s = sh*4 + sl;
    const int cb = s*8;
    const int jbase = cb*128;
    short8v bfr[4];
    {
      const size_t b = (size_t)(cb*8 + w)*6;
      #pragma unroll
      for (int k = 0; k < 4; ++k)
        bfr[k] = *(const short8v*)&Sbf[((b+k)*64 + l)*8];
    }
    const float sc = sqf[jbase + ncol];
    f32x4 acc0 = {0.f,0.f,0.f,0.f}, acc1 = {0.f,0.f,0.f,0.f};
    MFMA_PAIR6(acc0, afr[0], bfr);
    MFMA_PAIR6(acc1, afr[1], bfr);
    #pragma unroll
    for (int r = 0; r < 4; ++r) {
      const int q0 = qbase + 0*16 + (l >> 4)*4 + r;
      const int q1 = qbase + 1*16 + (l >> 4)*4 + r;
      sampD[(size_t)q0*1024 + s*128 + ncol] = sc - 2.0f*acc0[r];
      sampD[(size_t)q1*1024 + s*128 + ncol] = sc - 2.0f*acc1[r];
    }
  }
}

// ---------------- K2t: per-query threshold = 41st-smallest of 1024 samples ----------------
__global__ __launch_bounds__(256) void k2t_threshold(
    const float* __restrict__ sampD, float* __restrict__ Tq)
{
  const int w = threadIdx.x >> 6, l = threadIdx.x & 63;
  const int q = blockIdx.x*4 + w;
  unsigned ku[16];
  #pragma unroll
  for (int k = 0; k < 16; ++k)
    ku[k] = key_of(sampD[(size_t)q*1024 + k*64 + l]);
  unsigned prefix = 0; int need = 41;
  for (int b = 31; b >= 0; --b) {
    unsigned p2 = prefix << 1;
    int c = 0;
    #pragma unroll
    for (int k = 0; k < 16; ++k) c += ((ku[k] >> b) == p2);
    #pragma unroll
    for (int off = 32; off; off >>= 1) c += __shfl_xor(c, off);
    if (c >= need) prefix = p2; else { prefix = p2 | 1u; need -= c; }
  }
  if (l == 0) Tq[q] = key_inv(prefix);
}

// ---------------- K2f: streaming filter, LDS counters, grid 512 ----------------
__global__ __launch_bounds__(512) void k2f_filter(
    const unsigned short* __restrict__ Saf,
    const unsigned short* __restrict__ Sbf,
    const float* __restrict__ sqf,
    const float* __restrict__ Tq,
    int* __restrict__ cnt_g,
    float* __restrict__ survD, int* __restrict__ survI)
{
  __shared__ int cnt_sh[32];
  const int t = threadIdx.x, w = t >> 6, l = t & 63;
  const int qb = blockIdx.x >> 1, half = blockIdx.x & 1;
  const int qbase = qb * 32;
  if (t < 32) cnt_sh[t] = 0;
  short8v afr[2][4];
  float Tr[2][4]; int qloc[2][4];
  #pragma unroll
  for (int mt = 0; mt < 2; ++mt) {
    const size_t b = (size_t)(qb*2 + mt)*6;
    afr[mt][0] = *(const short8v*)&Saf[((b+0)*64 + l)*8];
    afr[mt][1] = *(const short8v*)&Saf[((b+1)*64 + l)*8];
    afr[mt][2] = *(const short8v*)&Saf[((b+4)*64 + l)*8];
    afr[mt][3] = *(const short8v*)&Saf[((b+5)*64 + l)*8];
    #pragma unroll
    for (int r = 0; r < 4; ++r) {
      qloc[mt][r] = mt*16 + (l >> 4)*4 + r;
      Tr[mt][r] = Tq[qbase + qloc[mt][r]];
    }
  }
  short8v bfr[4];
  {
    const size_t b = (size_t)(half*256 + w)*6;
    #pragma unroll
    for (int k = 0; k < 4; ++k)
      bfr[k] = *(const short8v*)&Sbf[((b+k)*64 + l)*8];
  }
  const int ncol = w*16 + (l & 15);
  __syncthreads();
  for (int cb = 0; cb < 32; ++cb) {
    const int jbase = half*4096 + cb*128;
    const float sc = sqf[jbase + ncol];
    f32x4 acc0 = {0.f,0.f,0.f,0.f}, acc1 = {0.f,0.f,0.f,0.f};
    MFMA_PAIR6(acc0, afr[0], bfr);
    MFMA_PAIR6(acc1, afr[1], bfr);
    if (cb < 31) {
      const size_t b = (size_t)(half*256 + (cb+1)*8 + w)*6;
      #pragma unroll
      for (int k = 0; k < 4; ++k)
        bfr[k] = *(const short8v*)&Sbf[((b+k)*64 + l)*8];
    }
    const int j = jbase + ncol;
    #pragma unroll
    for (int r = 0; r < 4; ++r) {
      float d0 = sc - 2.0f*acc0[r];
      if (d0 < Tr[0][r]) {
        int slot = atomicAdd(&cnt_sh[qloc[0][r]], 1);   // LDS atomic
        if (slot < SSEG) {
          size_t base = ((size_t)(qbase + qloc[0][r])*2 + half)*SSEG + slot;
          survD[base] = d0; survI[base] = j;
        }
      }
      float d1 = sc - 2.0f*acc1[r];
      if (d1 < Tr[1][r]) {
        int slot = atomicAdd(&cnt_sh[qloc[1][r]], 1);
        if (slot < SSEG) {
          size_t base = ((size_t)(qbase + qloc[1][r])*2 + half)*SSEG + slot;
          survD[base] = d1; survI[base] = j;
        }
      }
    }
  }
  __syncthreads();
  if (t < 32) cnt_g[(qbase + t)*2 + half] = cnt_sh[t];
}

// ---------------- K2s: exact fp32 top-48 of segmented survivors ----------------
__global__ __launch_bounds__(256) void k2s_select(
    const float* __restrict__ survD, const int* __restrict__ survI,
    const int* __restrict__ cnt_g, int* __restrict__ idx48)
{
  const int w = threadIdx.x >> 6, l = threadIdx.x & 63;
  const int node = blockIdx.x*4 + w;
  const int c0 = min(cnt_g[node*2 + 0], SSEG);
  const int c1 = min(cnt_g[node*2 + 1], SSEG);
  unsigned ku[10]; int iv[10];
  #pragma unroll
  for (int k = 0; k < 10; ++k) {
    int e = k*64 + l;
    int seg = (e >= SSEG);
    int off = e - seg*SSEG;
    bool v = off < (seg ? c1 : c0);
    size_t base = ((size_t)node*2 + seg)*SSEG + off;
    float d = v ? survD[base] : 0.f;
    iv[k] = v ? survI[base] : 0;
    ku[k] = v ? key_of(d) : 0xFFFFFFFFu;
  }
  unsigned prefix = 0; int need = KSEL;
  for (int b = 31; b >= 0; --b) {
    unsigned p2 = prefix << 1;
    int c = 0;
    #pragma unroll
    for (int k = 0; k < 10; ++k) c += ((ku[k] >> b) == p2);
    #pragma unroll
    for (int off = 32; off; off >>= 1) c += __shfl_xor(c, off);
    if (c >= need) prefix = p2; else { prefix = p2 | 1u; need -= c; }
  }
  const unsigned long long below = (1ull << l) - 1ull;
  int base = 0;
  #pragma unroll
  for (int k = 0; k < 10; ++k) {
    unsigned long long blt = __ballot(ku[k] < prefix);
    if (ku[k] < prefix) {
      int pos = base + __popcll(blt & below);
      idx48[(size_t)node*KSEL + pos] = iv[k];
    }
    base += __popcll(blt);
  }
  #pragma unroll
  for (int k = 0; k < 10; ++k) {
    unsigned long long beq = __ballot(ku[k] == prefix);
    if (ku[k] == prefix) {
      int pos = base + __popcll(beq & below);
      if (pos < KSEL) idx48[(size_t)node*KSEL + pos] = iv[k];
    }
    base += __popcll(beq);
  }
}

// ---------------- K2r: fp64 exact re-rank of the 48 -> sorted idx40 ----------------
__global__ __launch_bounds__(256) void k2r_rerank(
    const double* __restrict__ f64d, const double* __restrict__ sq64,
    const int* __restrict__ idx48, int* __restrict__ idx40)
{
  __shared__ double part[KSEL][4];
  __shared__ double dist_sh[KSEL];
  __shared__ int    cand_sh[KSEL];
  const int t = threadIdx.x;
  const int node = blockIdx.x;
  if (t < KSEL) cand_sh[t] = idx48[(size_t)node*KSEL + t];
  __syncthreads();
  if (t < 192) {
    int c = t >> 2, qt = t & 3;
    int cand = cand_sh[c];
    const double* fi = f64d + (size_t)node*DD + qt*16;
    const double* fc = f64d + (size_t)cand*DD + qt*16;
    double a0 = 0.0, a1 = 0.0;
    #pragma unroll
    for (int d = 0; d < 16; d += 2) { a0 += fi[d]*fc[d]; a1 += fi[d+1]*fc[d+1]; }
    part[c][qt] = a0 + a1;
  }
  __syncthreads();
  if (t < KSEL) {
    int cand = cand_sh[t];
    dist_sh[t] = sq64[node] + sq64[cand]
               - 2.0*(part[t][0] + part[t][1] + part[t][2] + part[t][3]);
  }
  __syncthreads();
  if (t < KSEL) {
    double dm = dist_sh[t]; int cand = cand_sh[t];
    int rank = 0;
    for (int j = 0; j < KSEL; ++j) {
      double dj = dist_sh[j];
      int    ij = cand_sh[j];
      rank += (dj < dm) || (dj == dm && ij < cand);
    }
    if (rank < 40) idx40[(size_t)node*40 + rank] = cand;
  }
}

#define MFMA6(ACC, AF, W0, W1, W2, W3)                                          \
  ACC = __builtin_amdgcn_mfma_f32_16x16x32_bf16(AF[0], W0, ACC, 0, 0, 0);       \
  ACC = __builtin_amdgcn_mfma_f32_16x16x32_bf16(AF[1], W1, ACC, 0, 0, 0);       \
  ACC = __builtin_amdgcn_mfma_f32_16x16x32_bf16(AF[0], W2, ACC, 0, 0, 0);       \
  ACC = __builtin_amdgcn_mfma_f32_16x16x32_bf16(AF[1], W3, ACC, 0, 0, 0);       \
  ACC = __builtin_amdgcn_mfma_f32_16x16x32_bf16(AF[2], W0, ACC, 0, 0, 0);       \
  ACC = __builtin_amdgcn_mfma_f32_16x16x32_bf16(AF[3], W1, ACC, 0, 0, 0);

// ---------------- K3: MFMA edge-convs, register-direct z, packed-a transpose ----------------
// Block per node. 4 waves: wave w -> m-tile (w>>1), n-tiles {2*(w&1), 2*(w&1)+1}.
__global__ __launch_bounds__(256) void k3_edgeconv(
    const float* __restrict__ f32v,
    const float* __restrict__ u1, const float* __restrict__ c1,
    const float* __restrict__ u2, const float* __restrict__ c2,
    const unsigned short* __restrict__ F1a, const unsigned short* __restrict__ F1b,
    const unsigned short* __restrict__ F2a, const unsigned short* __restrict__ F2b,
    const float* __restrict__ bm1a, const float* __restrict__ bm1b,
    const float* __restrict__ bm2a, const float* __restrict__ bm2b,
    const int* __restrict__ idx40, float* __restrict__ hout)
{
  __shared__ __align__(16) unsigned au32[32*66];   // a packed hi|lo<<16, stride 66
  __shared__ float red_s[2*64];
  __shared__ int idx_sh[40];
  const int t = threadIdx.x, i = blockIdx.x;
  const int w = t >> 6, l = t & 63;
  const int mt = w >> 1;
  const int nb0 = (w & 1)*2;
  const int row16 = l & 15;
  const int q8 = (l >> 4) << 3;
  if (t < 40) idx_sh[t] = idx40[i*40 + t];
  __syncthreads();

  for (int conv = 0; conv < 2; ++conv) {
    const float* u_g = conv ? u2 : u1;
    const float* c_g = conv ? c2 : c1;
    const unsigned short* WfA = conv ? F2a : F1a;
    const unsigned short* WfB = conv ? F2b : F1b;
    const float* bav = conv ? bm2a : bm1a;
    const float* bbv = conv ? bm2b : bm1b;

    // ---- z fragments register-direct from global (no LDS) ----
    const int row = mt*16 + row16;
    const bool valid = row < 20;
    const int nb = valid ? idx_sh[conv ? 2*row : row] : idx_sh[0];
    short8v afr[4];
    {
      const float* up = u_g + (size_t)nb*DD;
      const float* cp = c_g + (size_t)i*DD;
      float4 ua = *(const float4*)&up[q8];
      float4 ub = *(const float4*)&up[q8 + 4];
      float4 uc = *(const float4*)&up[32 + q8];
      float4 ud = *(const float4*)&up[32 + q8 + 4];
      float4 ca = *(const float4*)&cp[q8];
      float4 cb2 = *(const float4*)&cp[q8 + 4];
      float4 cc = *(const float4*)&cp[32 + q8];
      float4 cd = *(const float4*)&cp[32 + q8 + 4];
      float z0[8], z1[8];
      z0[0]=ca.x-ua.x;  z0[1]=ca.y-ua.y;  z0[2]=ca.z-ua.z;  z0[3]=ca.w-ua.w;
      z0[4]=cb2.x-ub.x; z0[5]=cb2.y-ub.y; z0[6]=cb2.z-ub.z; z0[7]=cb2.w-ub.w;
      z1[0]=cc.x-uc.x;  z1[1]=cc.y-uc.y;  z1[2]=cc.z-uc.z;  z1[3]=cc.w-uc.w;
      z1[4]=cd.x-ud.x;  z1[5]=cd.y-ud.y;  z1[6]=cd.z-ud.z;  z1[7]=cd.w-ud.w;
      union { unsigned short us[8]; short8v v; } fh0, fh1, fl0, fl1;
      #pragma unroll
      for (int j = 0; j < 8; ++j) {
        float x0 = valid ? LEAKY(z0[j]) : 0.f;
        float x1 = valid ? LEAKY(z1[j]) : 0.f;
        unsigned short h0 = f2bf(x0);
        unsigned short h1 = f2bf(x1);
        fh0.us[j] = h0; fl0.us[j] = f2bf(x0 - bf2f(h0));
        fh1.us[j] = h1; fl1.us[j] = f2bf(x1 - bf2f(h1));
      }
      afr[0] = fh0.v; afr[1] = fh1.v; afr[2] = fl0.v; afr[3] = fl1.v;
    }
    // ---- layer A ----
    f32x4 acc0 = {0.f,0.f,0.f,0.f}, acc1 = {0.f,0.f,0.f,0.f};
    {
      const unsigned short* p0 = WfA + ((size_t)(nb0+0)*6*64)*8;
      const unsigned short* p1 = WfA + ((size_t)(nb0+1)*6*64)*8;
      short8v w00 = *(const short8v*)&p0[(0*64+l)*8];
      short8v w01 = *(const short8v*)&p0[(1*64+l)*8];
      short8v w02 = *(const short8v*)&p0[(2*64+l)*8];
      short8v w03 = *(const short8v*)&p0[(3*64+l)*8];
      short8v w10 = *(const short8v*)&p1[(0*64+l)*8];
      short8v w11 = *(const short8v*)&p1[(1*64+l)*8];
      short8v w12 = *(const short8v*)&p1[(2*64+l)*8];
      short8v w13 = *(const short8v*)&p1[(3*64+l)*8];
      MFMA6(acc0, afr, w00, w01, w02, w03);
      MFMA6(acc1, afr, w10, w11, w12, w13);
    }
    // ---- epilogue A: leaky + pack hi/lo at write ----
    {
      const int c0 = (nb0+0)*16 + row16, c1i = (nb0+1)*16 + row16;
      const float ba0 = bav[c0], ba1 = bav[c1i];
      #pragma unroll
      for (int r = 0; r < 4; ++r) {
        const int arow = mt*16 + (l >> 4)*4 + r;
        float v0 = acc0[r] + ba0; v0 = LEAKY(v0);
        float v1 = acc1[r] + ba1; v1 = LEAKY(v1);
        unsigned short h0 = f2bf(v0), h1 = f2bf(v1);
        unsigned lo0 = f2bf(v0 - bf2f(h0));
        unsigned lo1 = f2bf(v1 - bf2f(h1));
        au32[arow*66 + c0]  = (unsigned)h0 | (lo0 << 16);
        au32[arow*66 + c1i] = (unsigned)h1 | (lo1 << 16);
      }
    }
    __syncthreads();
    // ---- layer B: fragments from packed au32 (b64 reads + shift unpack) ----
    short8v bfr[4];
    {
      const int base = (mt*16 + row16)*66 + q8;
      union { unsigned u[4]; short8v v; } bh0, bh1, bl0, bl1;
      #pragma unroll
      for (int p = 0; p < 4; ++p) {
        uint2 lo2 = *(const uint2*)&au32[base + 2*p];
        uint2 hi2 = *(const uint2*)&au32[base + 32 + 2*p];
        bh0.u[p] = (lo2.x & 0xFFFFu) | (lo2.y << 16);
        bl0.u[p] = (lo2.x >> 16)     | (lo2.y & 0xFFFF0000u);
        bh1.u[p] = (hi2.x & 0xFFFFu) | (hi2.y << 16);
        bl1.u[p] = (hi2.x >> 16)     | (hi2.y & 0xFFFF0000u);
      }
      bfr[0] = bh0.v; bfr[1] = bh1.v; bfr[2] = bl0.v; bfr[3] = bl1.v;
    }
    f32x4 bacc0 = {0.f,0.f,0.f,0.f}, bacc1 = {0.f,0.f,0.f,0.f};
    {
      const unsigned short* p0 = WfB + ((size_t)(nb0+0)*6*64)*8;
      const unsigned short* p1 = WfB + ((size_t)(nb0+1)*6*64)*8;
      short8v w00 = *(const short8v*)&p0[(0*64+l)*8];
      short8v w01 = *(const short8v*)&p0[(1*64+l)*8];
      short8v w02 = *(const short8v*)&p0[(2*64+l)*8];
      short8v w03 = *(const short8v*)&p0[(3*64+l)*8];
      short8v w10 = *(const short8v*)&p1[(0*64+l)*8];
      short8v w11 = *(const short8v*)&p1[(1*64+l)*8];
      short8v w12 = *(const short8v*)&p1[(2*64+l)*8];
      short8v w13 = *(const short8v*)&p1[(3*64+l)*8];
      MFMA6(bacc0, bfr, w00, w01, w02, w03);
      MFMA6(bacc1, bfr, w10, w11, w12, w13);
    }
    {
      const int c0 = (nb0+0)*16 + row16, c1i = (nb0+1)*16 + row16;
      const float bb0 = bbv[c0], bb1 = bbv[c1i];
      float m0 = -__builtin_inff(), m1 = -__builtin_inff();
      #pragma unroll
      for (int r = 0; r < 4; ++r) {
        const int arow = mt*16 + (l >> 4)*4 + r;
        if (arow < 20) {
          m0 = fmaxf(m0, bacc0[r] + bb0);
          m1 = fmaxf(m1, bacc1[r] + bb1);
        }
      }
      m0 = fmaxf(m0, __shfl_xor(m0, 16)); m0 = fmaxf(m0, __shfl_xor(m0, 32));
      m1 = fmaxf(m1, __shfl_xor(m1, 16)); m1 = fmaxf(m1, __shfl_xor(m1, 32));
      if ((l >> 4) == 0) {
        red_s[mt*64 + c0]  = m0;
        red_s[mt*64 + c1i] = m1;
      }
    }
    __syncthreads();
    if (t < 64) hout[i*192 + conv*64 + t] = fmaxf(red_s[t], red_s[64 + t]);
    __syncthreads();
  }
  if (t < 64) {
    float m = -__builtin_inff();
    #pragma unroll
    for (int k = 0; k < 9; ++k) m = fmaxf(m, f32v[idx_sh[k]*DD + t]);
    hout[i*192 + 128 + t] = m;
  }
}

// ---------------- K4: final linear + bias + residual ----------------
__global__ __launch_bounds__(256) void k4_final(
    const float* __restrict__ hbuf, const float* __restrict__ WlT,
    const float* __restrict__ bl, const float* __restrict__ feature,
    float* __restrict__ out)
{
  __shared__ __align__(16) float h_sh[16*192];
  const int t = threadIdx.x;
  const int nbase = blockIdx.x * 16;
  #pragma unroll
  for (int r = 0; r < 3; ++r) {
    int flat = t + 256*r;
    int n = flat / 48, j4 = flat % 48;
    *(float4*)&h_sh[n*192 + 4*j4] = *(const float4*)&hbuf[(nbase+n)*192 + 4*j4];
  }
  __syncthreads();
  float acc[16];
  #pragma unroll
  for (int n = 0; n < 16; ++n) acc[n] = 0.f;
  for (int j4 = 0; j4 < 48; ++j4) {
    float w0 = WlT[(4*j4+0)*256 + t];
    float w1 = WlT[(4*j4+1)*256 + t];
    float w2 = WlT[(4*j4+2)*256 + t];
    float w3 = WlT[(4*j4+3)*256 + t];
    #pragma unroll
    for (int n = 0; n < 16; ++n) {
      float4 hv = *(const float4*)&h_sh[n*192 + 4*j4];
      acc[n] += hv.x*w0 + hv.y*w1 + hv.z*w2 + hv.w*w3;
    }
  }
  float blv = bl[t];
  #pragma unroll
  for (int n = 0; n < 16; ++n)
    out[(nbase+n)*256 + t] = acc[n] + blv + feature[(nbase+n)*256 + t];
}

extern "C" void kernel_launch(void* const* d_in, const int* in_sizes, int n_in,
                              void* d_out, int out_size, void* d_ws, size_t ws_size,
                              hipStream_t stream) {
  const float* feature = (const float*)d_in[0];
  const float* Wb   = (const float*)d_in[1];
  const float* bb   = (const float*)d_in[2];
  const float* Wt1  = (const float*)d_in[3];
  const float* bt1  = (const float*)d_in[4];
  const float* Wp1  = (const float*)d_in[5];
  const float* bp1  = (const float*)d_in[6];
  const float* Wm1a = (const float*)d_in[7];
  const float* bm1a = (const float*)d_in[8];
  const float* Wm1b = (const float*)d_in[9];
  const float* bm1b = (const float*)d_in[10];
  const float* Wt2  = (const float*)d_in[11];
  const float* bt2  = (const float*)d_in[12];
  const float* Wp2  = (const float*)d_in[13];
  const float* bp2  = (const float*)d_in[14];
  const float* Wm2a = (const float*)d_in[15];
  const float* bm2a = (const float*)d_in[16];
  const float* Wm2b = (const float*)d_in[17];
  const float* bm2b = (const float*)d_in[18];
  const float* Wl   = (const float*)d_in[19];
  const float* bl   = (const float*)d_in[20];
  float* out = (float*)d_out;

  char* ws = (char*)d_ws;
  double* f64d = (double*)(ws + 0);
  double* sq64 = (double*)(ws + 4194304);
  float*  f32v = (float*)(ws + 4259840);
  float*  sqf  = (float*)(ws + 6356992);
  float*  u1   = (float*)(ws + 6389760);
  float*  c1   = (float*)(ws + 8486912);
  float*  u2   = (float*)(ws + 10584064);
  float*  c2   = (float*)(ws + 12681216);
  int*    idx48= (int*)(ws + 14778368);
  int*    idx40= (int*)(ws + 16351232);
  float*  hbuf = (float*)(ws + 17661952);
  float*  WlT  = (float*)(ws + 23953408);
  unsigned short* Saf = (unsigned short*)(ws + 24150016);
  unsigned short* Sbf = (unsigned short*)(ws + 27295744);
  float*  WbT  = (float*)(ws + 30441472);
  float*  WtT1 = (float*)(ws + 30507008);
  float*  WpT1 = (float*)(ws + 30523392);
  float*  WtT2 = (float*)(ws + 30539776);
  float*  WpT2 = (float*)(ws + 30556160);
  unsigned short* F1a = (unsigned short*)(ws + 30572544);
  unsigned short* F1b = (unsigned short*)(ws + 30597120);
  unsigned short* F2a = (unsigned short*)(ws + 30621696);
  unsigned short* F2b = (unsigned short*)(ws + 30646272);
  float*  Tq   = (float*)(ws + 30670848);
  int*    cnt_g= (int*)(ws + 30703616);
  float*  survD= (float*)(ws + 30769152);
  int*    survI= (int*)(ws + 51740672);
  float*  sampD= (float*)(ws + 30769152);   // aliases surv (dead before k2f)

  hipLaunchKernelGGL(k0_prep, dim3(260), dim3(256), 0, stream,
                     Wl, Wb, Wt1, Wp1, Wt2, Wp2, WlT, WbT, WtT1, WpT1, WtT2, WpT2);
  hipLaunchKernelGGL(k1c_wfrag, dim3(24), dim3(256), 0, stream,
                     Wm1a, Wm1b, Wm2a, Wm2b, F1a, F1b, F2a, F2b);
  hipLaunchKernelGGL(k1_precompute, dim3(2048), dim3(256), 0, stream,
                     feature, WbT, bb, WtT1, bt1, WpT1, bp1, WtT2, bt2, WpT2, bp2,
                     f64d, sq64, f32v, sqf, u1, c1, u2, c2);
  hipLaunchKernelGGL(k1b_frag, dim3(768), dim3(256), 0, stream, f32v, Saf, Sbf);
  hipLaunchKernelGGL(k2a_sample, dim3(512), dim3(512), 0, stream, Saf, Sbf, sqf, sampD);
  hipLaunchKernelGGL(k2t_threshold, dim3(2048), dim3(256), 0, stream, sampD, Tq);
  hipLaunchKernelGGL(k2f_filter, dim3(512), dim3(512), 0, stream,
                     Saf, Sbf, sqf, Tq, cnt_g, survD, survI);
  hipLaunchKernelGGL(k2s_select, dim3(2048), dim3(256), 0, stream, survD, survI, cnt_g, idx48);
  hipLaunchKernelGGL(k2r_rerank, dim3(8192), dim3(256), 0, stream, f64d, sq64, idx48, idx40);
  hipLaunchKernelGGL(k3_edgeconv, dim3(8192), dim3(256), 0, stream,
                     f32v, u1, c1, u2, c2, F1a, F1b, F2a, F2b,
                     bm1a, bm1b, bm2a, bm2b, idx40, hbuf);
  hipLaunchKernelGGL(k4_final, dim3(512), dim3(256), 0, stream, hbuf, WlT, bl, feature, out);
}

// Round 12
// 396.726 us; speedup vs baseline: 1.0904x; 1.0904x over previous
//
#include <hip/hip_runtime.h>
#include <math.h>

#define NPT   8192
#define FIN   256
#define DD    64
#define KSEL  48
#define SSEG  320

#define LEAKY(x) (((x) >= 0.f) ? (x) : 0.01f*(x))

using short8v = __attribute__((ext_vector_type(8))) short;
using f32x4   = __attribute__((ext_vector_type(4))) float;

__device__ inline unsigned short f2bf(float x) {
  union { float f; unsigned u; } v; v.f = x;
  unsigned r = v.u + 0x7fff + ((v.u >> 16) & 1);   // RNE
  return (unsigned short)(r >> 16);
}
__device__ inline float bf2f(unsigned short h) {
  union { unsigned u; float f; } v; v.u = ((unsigned)h) << 16; return v.f;
}
__device__ inline unsigned key_of(float f) {
  unsigned u = __float_as_uint(f);
  return (u & 0x80000000u) ? ~u : (u | 0x80000000u);
}
__device__ inline float key_inv(unsigned k) {
  unsigned u = (k >> 31) ? (k ^ 0x80000000u) : ~k;
  return __uint_as_float(u);
}

// ---------------- K0: transposes ----------------
__global__ void k0_prep(const float* __restrict__ Wl, const float* __restrict__ Wb,
                        const float* __restrict__ Wt1, const float* __restrict__ Wp1,
                        const float* __restrict__ Wt2, const float* __restrict__ Wp2,
                        float* __restrict__ WlT, float* __restrict__ WbT,
                        float* __restrict__ WtT1, float* __restrict__ WpT1,
                        float* __restrict__ WtT2, float* __restrict__ WpT2)
{
  const int b = blockIdx.x, t = threadIdx.x;
  if (b < 192) {
    WlT[b*256 + t] = Wl[t*192 + b];
  } else if (b < 256) {
    int j = (b - 192)*4 + (t >> 6), o = t & 63;
    WbT[j*64 + o] = Wb[o*256 + j];
  } else {
    int m = b - 256;
    const float* src = (m==0) ? Wt1 : (m==1) ? Wp1 : (m==2) ? Wt2 : Wp2;
    float*       dst = (m==0) ? WtT1: (m==1) ? WpT1: (m==2) ? WtT2: WpT2;
    #pragma unroll
    for (int i = 0; i < 16; ++i) {
      int idx = t + 256*i, r = idx >> 6, c = idx & 63;
      dst[c*64 + r] = src[r*64 + c];
    }
  }
}

// ---------------- K1: per-node precompute (4-acc fp64 ILP) ----------------
__global__ __launch_bounds__(256) void k1_precompute(
    const float* __restrict__ feature, const float* __restrict__ WbT, const float* __restrict__ bb,
    const float* __restrict__ WtT1, const float* __restrict__ bt1,
    const float* __restrict__ WpT1, const float* __restrict__ bp1,
    const float* __restrict__ WtT2, const float* __restrict__ bt2,
    const float* __restrict__ WpT2, const float* __restrict__ bp2,
    double* __restrict__ f64d, double* __restrict__ sq64,
    float* __restrict__ f32v, float* __restrict__ sqf,
    float* __restrict__ u1, float* __restrict__ c1,
    float* __restrict__ u2, float* __restrict__ c2)
{
  __shared__ float f_s[4*64];
  const int w = threadIdx.x >> 6, l = threadIdx.x & 63;
  const int i = blockIdx.x*4 + w;
  const float* frow = feature + i*FIN;
  double a0 = (double)bb[l], a1 = 0.0, a2 = 0.0, a3 = 0.0;
  #pragma unroll 2
  for (int j = 0; j < FIN; j += 4) {
    float4 fv = *(const float4*)&frow[j];
    a0 += (double)fv.x * (double)WbT[(j+0)*64 + l];
    a1 += (double)fv.y * (double)WbT[(j+1)*64 + l];
    a2 += (double)fv.z * (double)WbT[(j+2)*64 + l];
    a3 += (double)fv.w * (double)WbT[(j+3)*64 + l];
  }
  double facc = (a0 + a1) + (a2 + a3);
  f64d[i*DD + l] = facc;
  float f32 = (float)facc;
  f32v[i*DD + l] = f32;
  double s = facc*facc;
  #pragma unroll
  for (int off = 32; off; off >>= 1) s += __shfl_xor(s, off);
  if (l == 0) { sq64[i] = s; sqf[i] = (float)s; }
  f_s[w*64 + l] = f32;
  float au1 = 0.f, ap1 = 0.f, au2 = 0.f, ap2 = 0.f;
  for (int e = 0; e < DD; ++e) {
    float fe = f_s[w*64 + e];
    au1 += fe * WtT1[e*64 + l];
    ap1 += fe * WpT1[e*64 + l];
    au2 += fe * WtT2[e*64 + l];
    ap2 += fe * WpT2[e*64 + l];
  }
  u1[i*DD+l] = au1;
  c1[i*DD+l] = ap1 + bp1[l] + au1 + bt1[l];
  u2[i*DD+l] = au2;
  c2[i*DD+l] = ap2 + bp2[l] + au2 + bt2[l];
}

// ---------------- K1b: MFMA fragments for KNN (bf16 hi/lo) ----------------
__global__ __launch_bounds__(256) void k1b_frag(
    const float* __restrict__ f32v,
    unsigned short* __restrict__ Saf, unsigned short* __restrict__ Sbf)
{
  const int w = threadIdx.x >> 6, l = threadIdx.x & 63;
  const int task = blockIdx.x*4 + w;          // 0..3071
  const int tile = task / 6, ks = task % 6;
  const int row  = tile*16 + (l & 15);
  const int inner = (ks & 1)*32 + ((l >> 4) << 3);
  union { unsigned short u[8]; short8v v; } pa, pb;
  #pragma unroll
  for (int j = 0; j < 8; ++j) {
    float x = f32v[row*64 + inner + j];
    unsigned short hi = f2bf(x);
    unsigned short lo = f2bf(x - bf2f(hi));
    pa.u[j] = (ks < 4) ? hi : lo;
    pb.u[j] = (ks < 2) ? hi : ((ks < 4) ? lo : hi);
  }
  size_t off = ((size_t)(tile*6 + ks)*64 + l)*8;
  *(short8v*)&Saf[off] = pa.v;
  *(short8v*)&Sbf[off] = pb.v;
}

// ---------------- K1c: weight B-fragments for edge-conv MLPs ----------------
__global__ __launch_bounds__(256) void k1c_wfrag(
    const float* __restrict__ Wm1a, const float* __restrict__ Wm1b,
    const float* __restrict__ Wm2a, const float* __restrict__ Wm2b,
    unsigned short* __restrict__ F1a, unsigned short* __restrict__ F1b,
    unsigned short* __restrict__ F2a, unsigned short* __restrict__ F2b)
{
  const int w = threadIdx.x >> 6, l = threadIdx.x & 63;
  const int task = blockIdx.x*4 + w;          // 0..95
  const int which = task / 24, rem = task % 24;
  const int nt = rem / 6, ks = rem % 6;
  const float* W = (which==0) ? Wm1a : (which==1) ? Wm1b : (which==2) ? Wm2a : Wm2b;
  unsigned short* F = (which==0) ? F1a : (which==1) ? F1b : (which==2) ? F2a : F2b;
  const int row = nt*16 + (l & 15);
  const int inner = (ks & 1)*32 + ((l >> 4) << 3);
  union { unsigned short u[8]; short8v v; } p;
  #pragma unroll
  for (int j = 0; j < 8; ++j) {
    float x = W[row*64 + inner + j];
    unsigned short hi = f2bf(x);
    unsigned short lo = f2bf(x - bf2f(hi));
    p.u[j] = (ks < 2) ? hi : ((ks < 4) ? lo : hi);
  }
  *(short8v*)&F[((size_t)(nt*6 + ks)*64 + l)*8] = p.v;
}

#define MFMA_PAIR6(ACC, AF, BF)                                                  \
  ACC = __builtin_amdgcn_mfma_f32_16x16x32_bf16(AF[0], BF[0], ACC, 0, 0, 0);     \
  ACC = __builtin_amdgcn_mfma_f32_16x16x32_bf16(AF[1], BF[1], ACC, 0, 0, 0);     \
  ACC = __builtin_amdgcn_mfma_f32_16x16x32_bf16(AF[0], BF[2], ACC, 0, 0, 0);     \
  ACC = __builtin_amdgcn_mfma_f32_16x16x32_bf16(AF[1], BF[3], ACC, 0, 0, 0);     \
  ACC = __builtin_amdgcn_mfma_f32_16x16x32_bf16(AF[2], BF[0], ACC, 0, 0, 0);     \
  ACC = __builtin_amdgcn_mfma_f32_16x16x32_bf16(AF[3], BF[1], ACC, 0, 0, 0);

// ---------------- K2a: sampled distances (8 of 64 chunks), grid 512 ----------------
__global__ __launch_bounds__(512) void k2a_sample(
    const unsigned short* __restrict__ Saf,
    const unsigned short* __restrict__ Sbf,
    const float* __restrict__ sqf,
    float* __restrict__ sampD)
{
  const int t = threadIdx.x, w = t >> 6, l = t & 63;
  const int qb = blockIdx.x >> 1, sh = blockIdx.x & 1;
  const int qbase = qb * 32;
  short8v afr[2][4];
  #pragma unroll
  for (int mt = 0; mt < 2; ++mt) {
    const size_t b = (size_t)(qb*2 + mt)*6;
    afr[mt][0] = *(const short8v*)&Saf[((b+0)*64 + l)*8];
    afr[mt][1] = *(const short8v*)&Saf[((b+1)*64 + l)*8];
    afr[mt][2] = *(const short8v*)&Saf[((b+4)*64 + l)*8];
    afr[mt][3] = *(const short8v*)&Saf[((b+5)*64 + l)*8];
  }
  const int ncol = w*16 + (l & 15);
  for (int sl = 0; sl < 4; ++sl) {
    const int s = sh*4 + sl;
    const int cb = s*8;
    const int jbase = cb*128;
    short8v bfr[4];
    {
      const size_t b = (size_t)(cb*8 + w)*6;
      #pragma unroll
      for (int k = 0; k < 4; ++k)
        bfr[k] = *(const short8v*)&Sbf[((b+k)*64 + l)*8];
    }
    const float sc = sqf[jbase + ncol];
    f32x4 acc0 = {0.f,0.f,0.f,0.f}, acc1 = {0.f,0.f,0.f,0.f};
    MFMA_PAIR6(acc0, afr[0], bfr);
    MFMA_PAIR6(acc1, afr[1], bfr);
    #pragma unroll
    for (int r = 0; r < 4; ++r) {
      const int q0 = qbase + 0*16 + (l >> 4)*4 + r;
      const int q1 = qbase + 1*16 + (l >> 4)*4 + r;
      sampD[(size_t)q0*1024 + s*128 + ncol] = sc - 2.0f*acc0[r];
      sampD[(size_t)q1*1024 + s*128 + ncol] = sc - 2.0f*acc1[r];
    }
  }
}

// ---------------- K2t: per-query threshold = 41st-smallest of 1024 samples ----------------
__global__ __launch_bounds__(256) void k2t_threshold(
    const float* __restrict__ sampD, float* __restrict__ Tq)
{
  const int w = threadIdx.x >> 6, l = threadIdx.x & 63;
  const int q = blockIdx.x*4 + w;
  unsigned ku[16];
  #pragma unroll
  for (int k = 0; k < 16; ++k)
    ku[k] = key_of(sampD[(size_t)q*1024 + k*64 + l]);
  unsigned prefix = 0; int need = 41;
  for (int b = 31; b >= 0; --b) {
    unsigned p2 = prefix << 1;
    int c = 0;
    #pragma unroll
    for (int k = 0; k < 16; ++k) c += ((ku[k] >> b) == p2);
    #pragma unroll
    for (int off = 32; off; off >>= 1) c += __shfl_xor(c, off);
    if (c >= need) prefix = p2; else { prefix = p2 | 1u; need -= c; }
  }
  if (l == 0) Tq[q] = key_inv(prefix);
}

// ---------------- K2f: streaming filter, LDS counters, grid 512 ----------------
__global__ __launch_bounds__(512) void k2f_filter(
    const unsigned short* __restrict__ Saf,
    const unsigned short* __restrict__ Sbf,
    const float* __restrict__ sqf,
    const float* __restrict__ Tq,
    int* __restrict__ cnt_g,
    float* __restrict__ survD, int* __restrict__ survI)
{
  __shared__ int cnt_sh[32];
  const int t = threadIdx.x, w = t >> 6, l = t & 63;
  const int qb = blockIdx.x >> 1, half = blockIdx.x & 1;
  const int qbase = qb * 32;
  if (t < 32) cnt_sh[t] = 0;
  short8v afr[2][4];
  float Tr[2][4]; int qloc[2][4];
  #pragma unroll
  for (int mt = 0; mt < 2; ++mt) {
    const size_t b = (size_t)(qb*2 + mt)*6;
    afr[mt][0] = *(const short8v*)&Saf[((b+0)*64 + l)*8];
    afr[mt][1] = *(const short8v*)&Saf[((b+1)*64 + l)*8];
    afr[mt][2] = *(const short8v*)&Saf[((b+4)*64 + l)*8];
    afr[mt][3] = *(const short8v*)&Saf[((b+5)*64 + l)*8];
    #pragma unroll
    for (int r = 0; r < 4; ++r) {
      qloc[mt][r] = mt*16 + (l >> 4)*4 + r;
      Tr[mt][r] = Tq[qbase + qloc[mt][r]];
    }
  }
  short8v bfr[4];
  {
    const size_t b = (size_t)(half*256 + w)*6;
    #pragma unroll
    for (int k = 0; k < 4; ++k)
      bfr[k] = *(const short8v*)&Sbf[((b+k)*64 + l)*8];
  }
  const int ncol = w*16 + (l & 15);
  __syncthreads();
  for (int cb = 0; cb < 32; ++cb) {
    const int jbase = half*4096 + cb*128;
    const float sc = sqf[jbase + ncol];
    f32x4 acc0 = {0.f,0.f,0.f,0.f}, acc1 = {0.f,0.f,0.f,0.f};
    MFMA_PAIR6(acc0, afr[0], bfr);
    MFMA_PAIR6(acc1, afr[1], bfr);
    if (cb < 31) {
      const size_t b = (size_t)(half*256 + (cb+1)*8 + w)*6;
      #pragma unroll
      for (int k = 0; k < 4; ++k)
        bfr[k] = *(const short8v*)&Sbf[((b+k)*64 + l)*8];
    }
    const int j = jbase + ncol;
    #pragma unroll
    for (int r = 0; r < 4; ++r) {
      float d0 = sc - 2.0f*acc0[r];
      if (d0 < Tr[0][r]) {
        int slot = atomicAdd(&cnt_sh[qloc[0][r]], 1);   // LDS atomic
        if (slot < SSEG) {
          size_t base = ((size_t)(qbase + qloc[0][r])*2 + half)*SSEG + slot;
          survD[base] = d0; survI[base] = j;
        }
      }
      float d1 = sc - 2.0f*acc1[r];
      if (d1 < Tr[1][r]) {
        int slot = atomicAdd(&cnt_sh[qloc[1][r]], 1);
        if (slot < SSEG) {
          size_t base = ((size_t)(qbase + qloc[1][r])*2 + half)*SSEG + slot;
          survD[base] = d1; survI[base] = j;
        }
      }
    }
  }
  __syncthreads();
  if (t < 32) cnt_g[(qbase + t)*2 + half] = cnt_sh[t];
}

// ---------------- K2s: exact fp32 top-48 of segmented survivors ----------------
__global__ __launch_bounds__(256) void k2s_select(
    const float* __restrict__ survD, const int* __restrict__ survI,
    const int* __restrict__ cnt_g, int* __restrict__ idx48)
{
  const int w = threadIdx.x >> 6, l = threadIdx.x & 63;
  const int node = blockIdx.x*4 + w;
  const int c0 = min(cnt_g[node*2 + 0], SSEG);
  const int c1 = min(cnt_g[node*2 + 1], SSEG);
  unsigned ku[10]; int iv[10];
  #pragma unroll
  for (int k = 0; k < 10; ++k) {
    int e = k*64 + l;
    int seg = (e >= SSEG);
    int off = e - seg*SSEG;
    bool v = off < (seg ? c1 : c0);
    size_t base = ((size_t)node*2 + seg)*SSEG + off;
    float d = v ? survD[base] : 0.f;
    iv[k] = v ? survI[base] : 0;
    ku[k] = v ? key_of(d) : 0xFFFFFFFFu;
  }
  unsigned prefix = 0; int need = KSEL;
  for (int b = 31; b >= 0; --b) {
    unsigned p2 = prefix << 1;
    int c = 0;
    #pragma unroll
    for (int k = 0; k < 10; ++k) c += ((ku[k] >> b) == p2);
    #pragma unroll
    for (int off = 32; off; off >>= 1) c += __shfl_xor(c, off);
    if (c >= need) prefix = p2; else { prefix = p2 | 1u; need -= c; }
  }
  const unsigned long long below = (1ull << l) - 1ull;
  int base = 0;
  #pragma unroll
  for (int k = 0; k < 10; ++k) {
    unsigned long long blt = __ballot(ku[k] < prefix);
    if (ku[k] < prefix) {
      int pos = base + __popcll(blt & below);
      idx48[(size_t)node*KSEL + pos] = iv[k];
    }
    base += __popcll(blt);
  }
  #pragma unroll
  for (int k = 0; k < 10; ++k) {
    unsigned long long beq = __ballot(ku[k] == prefix);
    if (ku[k] == prefix) {
      int pos = base + __popcll(beq & below);
      if (pos < KSEL) idx48[(size_t)node*KSEL + pos] = iv[k];
    }
    base += __popcll(beq);
  }
}

// ---------------- K2r: fp64 exact re-rank of the 48 -> sorted idx40 ----------------
__global__ __launch_bounds__(256) void k2r_rerank(
    const double* __restrict__ f64d, const double* __restrict__ sq64,
    const int* __restrict__ idx48, int* __restrict__ idx40)
{
  __shared__ double part[KSEL][4];
  __shared__ double dist_sh[KSEL];
  __shared__ int    cand_sh[KSEL];
  const int t = threadIdx.x;
  const int node = blockIdx.x;
  if (t < KSEL) cand_sh[t] = idx48[(size_t)node*KSEL + t];
  __syncthreads();
  if (t < 192) {
    int c = t >> 2, qt = t & 3;
    int cand = cand_sh[c];
    const double* fi = f64d + (size_t)node*DD + qt*16;
    const double* fc = f64d + (size_t)cand*DD + qt*16;
    double a0 = 0.0, a1 = 0.0;
    #pragma unroll
    for (int d = 0; d < 16; d += 2) { a0 += fi[d]*fc[d]; a1 += fi[d+1]*fc[d+1]; }
    part[c][qt] = a0 + a1;
  }
  __syncthreads();
  if (t < KSEL) {
    int cand = cand_sh[t];
    dist_sh[t] = sq64[node] + sq64[cand]
               - 2.0*(part[t][0] + part[t][1] + part[t][2] + part[t][3]);
  }
  __syncthreads();
  if (t < KSEL) {
    double dm = dist_sh[t]; int cand = cand_sh[t];
    int rank = 0;
    for (int j = 0; j < KSEL; ++j) {
      double dj = dist_sh[j];
      int    ij = cand_sh[j];
      rank += (dj < dm) || (dj == dm && ij < cand);
    }
    if (rank < 40) idx40[(size_t)node*40 + rank] = cand;
  }
}

// ---------------- K3: MFMA edge-convs, hi-only bf16, 2 nodes/block ----------------
// 4 waves: wave w -> (sub = w>>1 node, mt = w&1 m-tile); each wave covers all 4 n-tiles.
__global__ __launch_bounds__(256) void k3_edgeconv(
    const float* __restrict__ f32v,
    const float* __restrict__ u1, const float* __restrict__ c1,
    const float* __restrict__ u2, const float* __restrict__ c2,
    const unsigned short* __restrict__ F1a, const unsigned short* __restrict__ F1b,
    const unsigned short* __restrict__ F2a, const unsigned short* __restrict__ F2b,
    const float* __restrict__ bm1a, const float* __restrict__ bm1b,
    const float* __restrict__ bm2a, const float* __restrict__ bm2b,
    const int* __restrict__ idx40, float* __restrict__ hout)
{
  __shared__ unsigned short au16[2][32*72];   // a as bf16, row stride 72
  __shared__ float red_s[2][2][64];
  __shared__ int idx_sh[80];
  const int t = threadIdx.x;
  const int w = t >> 6, l = t & 63;
  const int sub = w >> 1, mt = w & 1;
  const int i = blockIdx.x*2 + sub;
  const int row16 = l & 15;
  const int q8 = (l >> 4) << 3;
  if (t < 80) idx_sh[t] = idx40[(size_t)(blockIdx.x*2 + (t >= 40))*40 + (t >= 40 ? t - 40 : t)];
  __syncthreads();

  for (int conv = 0; conv < 2; ++conv) {
    const float* u_g = conv ? u2 : u1;
    const float* c_g = conv ? c2 : c1;
    const unsigned short* WfA = conv ? F2a : F1a;
    const unsigned short* WfB = conv ? F2b : F1b;
    const float* bav = conv ? bm2a : bm1a;
    const float* bbv = conv ? bm2b : bm1b;

    // ---- z fragments register-direct from global (hi-only bf16) ----
    const int row = mt*16 + row16;
    const bool valid = row < 20;
    const int nb = valid ? idx_sh[sub*40 + (conv ? 2*row : row)] : idx_sh[sub*40];
    short8v fr0, fr1;
    {
      const float* up = u_g + (size_t)nb*DD;
      const float* cp = c_g + (size_t)i*DD;
      float4 ua = *(const float4*)&up[q8];
      float4 ub = *(const float4*)&up[q8 + 4];
      float4 uc = *(const float4*)&up[32 + q8];
      float4 ud = *(const float4*)&up[32 + q8 + 4];
      float4 ca = *(const float4*)&cp[q8];
      float4 cb = *(const float4*)&cp[q8 + 4];
      float4 cc = *(const float4*)&cp[32 + q8];
      float4 cd = *(const float4*)&cp[32 + q8 + 4];
      float z0[8] = {ca.x-ua.x, ca.y-ua.y, ca.z-ua.z, ca.w-ua.w,
                     cb.x-ub.x, cb.y-ub.y, cb.z-ub.z, cb.w-ub.w};
      float z1[8] = {cc.x-uc.x, cc.y-uc.y, cc.z-uc.z, cc.w-uc.w,
                     cd.x-ud.x, cd.y-ud.y, cd.z-ud.z, cd.w-ud.w};
      union { unsigned short us[8]; short8v v; } h0, h1;
      #pragma unroll
      for (int j = 0; j < 8; ++j) {
        float x0 = valid ? LEAKY(z0[j]) : 0.f;
        float x1 = valid ? LEAKY(z1[j]) : 0.f;
        h0.us[j] = f2bf(x0);
        h1.us[j] = f2bf(x1);
      }
      fr0 = h0.v; fr1 = h1.v;
    }
    // ---- layer A: 4 n-tiles, hi-only (2 MFMA each) ----
    f32x4 acc[4] = {{0,0,0,0},{0,0,0,0},{0,0,0,0},{0,0,0,0}};
    #pragma unroll
    for (int nt = 0; nt < 4; ++nt) {
      const unsigned short* p = WfA + (size_t)nt*6*64*8;
      short8v w0 = *(const short8v*)&p[(0*64 + l)*8];
      short8v w1 = *(const short8v*)&p[(1*64 + l)*8];
      acc[nt] = __builtin_amdgcn_mfma_f32_16x16x32_bf16(fr0, w0, acc[nt], 0, 0, 0);
      acc[nt] = __builtin_amdgcn_mfma_f32_16x16x32_bf16(fr1, w1, acc[nt], 0, 0, 0);
    }
    // ---- epilogue A: bias + leaky + bf16 store to LDS ----
    #pragma unroll
    for (int nt = 0; nt < 4; ++nt) {
      const int col = nt*16 + row16;
      const float ba = bav[col];
      #pragma unroll
      for (int r = 0; r < 4; ++r) {
        const int arow = mt*16 + (l >> 4)*4 + r;
        float v = acc[nt][r] + ba; v = LEAKY(v);
        au16[sub][arow*72 + col] = f2bf(v);
      }
    }
    __syncthreads();
    // ---- layer B fragments from LDS (b128 reads, no repack) ----
    short8v g0, g1;
    {
      const unsigned short* base = &au16[sub][(mt*16 + row16)*72 + q8];
      g0 = *(const short8v*)&base[0];
      g1 = *(const short8v*)&base[32];
    }
    f32x4 bacc[4] = {{0,0,0,0},{0,0,0,0},{0,0,0,0},{0,0,0,0}};
    #pragma unroll
    for (int nt = 0; nt < 4; ++nt) {
      const unsigned short* p = WfB + (size_t)nt*6*64*8;
      short8v w0 = *(const short8v*)&p[(0*64 + l)*8];
      short8v w1 = *(const short8v*)&p[(1*64 + l)*8];
      bacc[nt] = __builtin_amdgcn_mfma_f32_16x16x32_bf16(g0, w0, bacc[nt], 0, 0, 0);
      bacc[nt] = __builtin_amdgcn_mfma_f32_16x16x32_bf16(g1, w1, bacc[nt], 0, 0, 0);
    }
    // ---- masked max over rows + cross-quad reduce ----
    #pragma unroll
    for (int nt = 0; nt < 4; ++nt) {
      const int col = nt*16 + row16;
      const float bb2 = bbv[col];
      float m = -__builtin_inff();
      #pragma unroll
      for (int r = 0; r < 4; ++r) {
        const int arow = mt*16 + (l >> 4)*4 + r;
        if (arow < 20) m = fmaxf(m, bacc[nt][r] + bb2);
      }
      m = fmaxf(m, __shfl_xor(m, 16));
      m = fmaxf(m, __shfl_xor(m, 32));
      if ((l >> 4) == 0) red_s[sub][mt][col] = m;
    }
    __syncthreads();
    if (t < 128) {
      int s2 = t >> 6, col = t & 63;
      hout[(size_t)(blockIdx.x*2 + s2)*192 + conv*64 + col] =
          fmaxf(red_s[s2][0][col], red_s[s2][1][col]);
    }
    __syncthreads();
  }
  // h_max over first 9 neighbors of f
  if (t < 128) {
    int s2 = t >> 6, col = t & 63;
    float m = -__builtin_inff();
    #pragma unroll
    for (int k = 0; k < 9; ++k)
      m = fmaxf(m, f32v[(size_t)idx_sh[s2*40 + k]*DD + col]);
    hout[(size_t)(blockIdx.x*2 + s2)*192 + 128 + col] = m;
  }
}

// ---------------- K4: final linear + bias + residual ----------------
__global__ __launch_bounds__(256) void k4_final(
    const float* __restrict__ hbuf, const float* __restrict__ WlT,
    const float* __restrict__ bl, const float* __restrict__ feature,
    float* __restrict__ out)
{
  __shared__ __align__(16) float h_sh[16*192];
  const int t = threadIdx.x;
  const int nbase = blockIdx.x * 16;
  #pragma unroll
  for (int r = 0; r < 3; ++r) {
    int flat = t + 256*r;
    int n = flat / 48, j4 = flat % 48;
    *(float4*)&h_sh[n*192 + 4*j4] = *(const float4*)&hbuf[(nbase+n)*192 + 4*j4];
  }
  __syncthreads();
  float acc[16];
  #pragma unroll
  for (int n = 0; n < 16; ++n) acc[n] = 0.f;
  for (int j4 = 0; j4 < 48; ++j4) {
    float w0 = WlT[(4*j4+0)*256 + t];
    float w1 = WlT[(4*j4+1)*256 + t];
    float w2 = WlT[(4*j4+2)*256 + t];
    float w3 = WlT[(4*j4+3)*256 + t];
    #pragma unroll
    for (int n = 0; n < 16; ++n) {
      float4 hv = *(const float4*)&h_sh[n*192 + 4*j4];
      acc[n] += hv.x*w0 + hv.y*w1 + hv.z*w2 + hv.w*w3;
    }
  }
  float blv = bl[t];
  #pragma unroll
  for (int n = 0; n < 16; ++n)
    out[(nbase+n)*256 + t] = acc[n] + blv + feature[(nbase+n)*256 + t];
}

extern "C" void kernel_launch(void* const* d_in, const int* in_sizes, int n_in,
                              void* d_out, int out_size, void* d_ws, size_t ws_size,
                              hipStream_t stream) {
  const float* feature = (const float*)d_in[0];
  const float* Wb   = (const float*)d_in[1];
  const float* bb   = (const float*)d_in[2];
  const float* Wt1  = (const float*)d_in[3];
  const float* bt1  = (const float*)d_in[4];
  const float* Wp1  = (const float*)d_in[5];
  const float* bp1  = (const float*)d_in[6];
  const float* Wm1a = (const float*)d_in[7];
  const float* bm1a = (const float*)d_in[8];
  const float* Wm1b = (const float*)d_in[9];
  const float* bm1b = (const float*)d_in[10];
  const float* Wt2  = (const float*)d_in[11];
  const float* bt2  = (const float*)d_in[12];
  const float* Wp2  = (const float*)d_in[13];
  const float* bp2  = (const float*)d_in[14];
  const float* Wm2a = (const float*)d_in[15];
  const float* bm2a = (const float*)d_in[16];
  const float* Wm2b = (const float*)d_in[17];
  const float* bm2b = (const float*)d_in[18];
  const float* Wl   = (const float*)d_in[19];
  const float* bl   = (const float*)d_in[20];
  float* out = (float*)d_out;

  char* ws = (char*)d_ws;
  double* f64d = (double*)(ws + 0);
  double* sq64 = (double*)(ws + 4194304);
  float*  f32v = (float*)(ws + 4259840);
  float*  sqf  = (float*)(ws + 6356992);
  float*  u1   = (float*)(ws + 6389760);
  float*  c1   = (float*)(ws + 8486912);
  float*  u2   = (float*)(ws + 10584064);
  float*  c2   = (float*)(ws + 12681216);
  int*    idx48= (int*)(ws + 14778368);
  int*    idx40= (int*)(ws + 16351232);
  float*  hbuf = (float*)(ws + 17661952);
  float*  WlT  = (float*)(ws + 23953408);
  unsigned short* Saf = (unsigned short*)(ws + 24150016);
  unsigned short* Sbf = (unsigned short*)(ws + 27295744);
  float*  WbT  = (float*)(ws + 30441472);
  float*  WtT1 = (float*)(ws + 30507008);
  float*  WpT1 = (float*)(ws + 30523392);
  float*  WtT2 = (float*)(ws + 30539776);
  float*  WpT2 = (float*)(ws + 30556160);
  unsigned short* F1a = (unsigned short*)(ws + 30572544);
  unsigned short* F1b = (unsigned short*)(ws + 30597120);
  unsigned short* F2a = (unsigned short*)(ws + 30621696);
  unsigned short* F2b = (unsigned short*)(ws + 30646272);
  float*  Tq   = (float*)(ws + 30670848);
  int*    cnt_g= (int*)(ws + 30703616);
  float*  survD= (float*)(ws + 30769152);
  int*    survI= (int*)(ws + 51740672);
  float*  sampD= (float*)(ws + 30769152);   // aliases surv (dead before k2f)

  hipLaunchKernelGGL(k0_prep, dim3(260), dim3(256), 0, stream,
                     Wl, Wb, Wt1, Wp1, Wt2, Wp2, WlT, WbT, WtT1, WpT1, WtT2, WpT2);
  hipLaunchKernelGGL(k1c_wfrag, dim3(24), dim3(256), 0, stream,
                     Wm1a, Wm1b, Wm2a, Wm2b, F1a, F1b, F2a, F2b);
  hipLaunchKernelGGL(k1_precompute, dim3(2048), dim3(256), 0, stream,
                     feature, WbT, bb, WtT1, bt1, WpT1, bp1, WtT2, bt2, WpT2, bp2,
                     f64d, sq64, f32v, sqf, u1, c1, u2, c2);
  hipLaunchKernelGGL(k1b_frag, dim3(768), dim3(256), 0, stream, f32v, Saf, Sbf);
  hipLaunchKernelGGL(k2a_sample, dim3(512), dim3(512), 0, stream, Saf, Sbf, sqf, sampD);
  hipLaunchKernelGGL(k2t_threshold, dim3(2048), dim3(256), 0, stream, sampD, Tq);
  hipLaunchKernelGGL(k2f_filter, dim3(512), dim3(512), 0, stream,
                     Saf, Sbf, sqf, Tq, cnt_g, survD, survI);
  hipLaunchKernelGGL(k2s_select, dim3(2048), dim3(256), 0, stream, survD, survI, cnt_g, idx48);
  hipLaunchKernelGGL(k2r_rerank, dim3(8192), dim3(256), 0, stream, f64d, sq64, idx48, idx40);
  hipLaunchKernelGGL(k3_edgeconv, dim3(4096), dim3(256), 0, stream,
                     f32v, u1, c1, u2, c2, F1a, F1b, F2a, F2b,
                     bm1a, bm1b, bm2a, bm2b, idx40, hbuf);
  hipLaunchKernelGGL(k4_final, dim3(512), dim3(256), 0, stream, hbuf, WlT, bl, feature, out);
}

// Round 13
// 378.722 us; speedup vs baseline: 1.1422x; 1.0475x over previous
//
#include <hip/hip_runtime.h>
#include <math.h>

#define NPT   8192
#define FIN   256
#define DD    64
#define KSEL  48
#define SSEG  320

#define LEAKY(x) (((x) >= 0.f) ? (x) : 0.01f*(x))

using short8v = __attribute__((ext_vector_type(8))) short;
using f32x4   = __attribute__((ext_vector_type(4))) float;

__device__ inline unsigned short f2bf(float x) {
  union { float f; unsigned u; } v; v.f = x;
  unsigned r = v.u + 0x7fff + ((v.u >> 16) & 1);   // RNE
  return (unsigned short)(r >> 16);
}
__device__ inline float bf2f(unsigned short h) {
  union { unsigned u; float f; } v; v.u = ((unsigned)h) << 16; return v.f;
}
__device__ inline unsigned key_of(float f) {
  unsigned u = __float_as_uint(f);
  return (u & 0x80000000u) ? ~u : (u | 0x80000000u);
}
__device__ inline float key_inv(unsigned k) {
  unsigned u = (k >> 31) ? (k ^ 0x80000000u) : ~k;
  return __uint_as_float(u);
}

// ---------------- K0: transposes (Wl, Wb only) ----------------
__global__ void k0_prep(const float* __restrict__ Wl, const float* __restrict__ Wb,
                        float* __restrict__ WlT, float* __restrict__ WbT)
{
  const int b = blockIdx.x, t = threadIdx.x;
  if (b < 192) {
    WlT[b*256 + t] = Wl[t*192 + b];
  } else {
    int j = (b - 192)*4 + (t >> 6), o = t & 63;
    WbT[j*64 + o] = Wb[o*256 + j];
  }
}

// ---------------- K1a: f (fp64) via LDS-staged WbT ----------------
// 512 thr (8 waves), 8 nodes/block, grid 1024. WbT staged as column-packed float4.
__global__ __launch_bounds__(512) void k1a_f64(
    const float* __restrict__ feature, const float* __restrict__ WbT,
    const float* __restrict__ bb,
    double* __restrict__ f64d, double* __restrict__ sq64,
    float* __restrict__ f32v, float* __restrict__ sqf)
{
  __shared__ __align__(16) float4 Q[64*64];   // Q[jj*64+col] = WbT[4jj..4jj+3][col], 64 KB
  const int t = threadIdx.x, w = t >> 6, l = t & 63;
  const int i = blockIdx.x*8 + w;
  #pragma unroll
  for (int r = 0; r < 8; ++r) {
    int flat = t + 512*r;
    int jj = flat >> 6, col = flat & 63;
    float4 q;
    q.x = WbT[(4*jj+0)*64 + col];
    q.y = WbT[(4*jj+1)*64 + col];
    q.z = WbT[(4*jj+2)*64 + col];
    q.w = WbT[(4*jj+3)*64 + col];
    Q[jj*64 + col] = q;
  }
  __syncthreads();
  const float* frow = feature + (size_t)i*FIN;
  double a0 = (double)bb[l], a1 = 0.0, a2 = 0.0, a3 = 0.0;
  #pragma unroll 4
  for (int jj = 0; jj < 64; ++jj) {
    float4 fv = *(const float4*)&frow[4*jj];   // wave-uniform
    float4 q = Q[jj*64 + l];                   // canonical b128, conflict-free
    a0 += (double)fv.x * (double)q.x;
    a1 += (double)fv.y * (double)q.y;
    a2 += (double)fv.z * (double)q.z;
    a3 += (double)fv.w * (double)q.w;
  }
  double facc = (a0 + a1) + (a2 + a3);
  f64d[(size_t)i*DD + l] = facc;
  float f32 = (float)facc;
  f32v[(size_t)i*DD + l] = f32;
  double s = facc*facc;
  #pragma unroll
  for (int off = 32; off; off >>= 1) s += __shfl_xor(s, off);
  if (l == 0) { sq64[i] = s; sqf[i] = (float)s; }
}

// ---------------- K1b: MFMA fragments for KNN (bf16 hi/lo) ----------------
__global__ __launch_bounds__(256) void k1b_frag(
    const float* __restrict__ f32v,
    unsigned short* __restrict__ Saf, unsigned short* __restrict__ Sbf)
{
  const int w = threadIdx.x >> 6, l = threadIdx.x & 63;
  const int task = blockIdx.x*4 + w;          // 0..3071
  const int tile = task / 6, ks = task % 6;
  const int row  = tile*16 + (l & 15);
  const int inner = (ks & 1)*32 + ((l >> 4) << 3);
  union { unsigned short u[8]; short8v v; } pa, pb;
  #pragma unroll
  for (int j = 0; j < 8; ++j) {
    float x = f32v[row*64 + inner + j];
    unsigned short hi = f2bf(x);
    unsigned short lo = f2bf(x - bf2f(hi));
    pa.u[j] = (ks < 4) ? hi : lo;
    pb.u[j] = (ks < 2) ? hi : ((ks < 4) ? lo : hi);
  }
  size_t off = ((size_t)(tile*6 + ks)*64 + l)*8;
  *(short8v*)&Saf[off] = pa.v;
  *(short8v*)&Sbf[off] = pb.v;
}

// ---------------- K1c: weight B-fragments (8 mats, runs after k2r) ----------------
// which: 0..3 = Wm1a,Wm1b,Wm2a,Wm2b ; 4=Wt1 ; 5=Wt1+Wp1 ; 6=Wt2 ; 7=Wt2+Wp2
__global__ __launch_bounds__(256) void k1c_wfrag(
    const float* __restrict__ Wm1a, const float* __restrict__ Wm1b,
    const float* __restrict__ Wm2a, const float* __restrict__ Wm2b,
    const float* __restrict__ Wt1, const float* __restrict__ Wp1,
    const float* __restrict__ Wt2, const float* __restrict__ Wp2,
    unsigned short* __restrict__ F1a, unsigned short* __restrict__ F1b,
    unsigned short* __restrict__ F2a, unsigned short* __restrict__ F2b,
    unsigned short* __restrict__ Gu1, unsigned short* __restrict__ Gc1,
    unsigned short* __restrict__ Gu2, unsigned short* __restrict__ Gc2)
{
  const int w = threadIdx.x >> 6, l = threadIdx.x & 63;
  const int task = blockIdx.x*4 + w;          // 0..191
  const int which = task / 24, rem = task % 24;
  const int nt = rem / 6, ks = rem % 6;
  const float* W  = (which==0) ? Wm1a : (which==1) ? Wm1b : (which==2) ? Wm2a :
                    (which==3) ? Wm2b : (which==4) ? Wt1  : (which==5) ? Wt1  :
                    (which==6) ? Wt2  : Wt2;
  const float* W2 = (which==5) ? Wp1 : (which==7) ? Wp2 : (const float*)0;
  unsigned short* F = (which==0) ? F1a : (which==1) ? F1b : (which==2) ? F2a :
                      (which==3) ? F2b : (which==4) ? Gu1 : (which==5) ? Gc1 :
                      (which==6) ? Gu2 : Gc2;
  const int row = nt*16 + (l & 15);
  const int inner = (ks & 1)*32 + ((l >> 4) << 3);
  union { unsigned short u[8]; short8v v; } p;
  #pragma unroll
  for (int j = 0; j < 8; ++j) {
    float x = W[row*64 + inner + j];
    if (W2) x += W2[row*64 + inner + j];
    unsigned short hi = f2bf(x);
    unsigned short lo = f2bf(x - bf2f(hi));
    p.u[j] = (ks < 2) ? hi : ((ks < 4) ? lo : hi);
  }
  *(short8v*)&F[((size_t)(nt*6 + ks)*64 + l)*8] = p.v;
}

// ---------------- K1d: u/c via MFMA (hi/lo 3-term), runs after k1c ----------------
// u = f@Wt.T ; c = f@(Wt+Wp).T + (bt+bp). Wave per m-tile, grid 128.
__global__ __launch_bounds__(256) void k1d_uc(
    const unsigned short* __restrict__ Saf,
    const unsigned short* __restrict__ Gu1, const unsigned short* __restrict__ Gc1,
    const unsigned short* __restrict__ Gu2, const unsigned short* __restrict__ Gc2,
    const float* __restrict__ bt1, const float* __restrict__ bp1,
    const float* __restrict__ bt2, const float* __restrict__ bp2,
    float* __restrict__ u1, float* __restrict__ c1,
    float* __restrict__ u2, float* __restrict__ c2)
{
  const int t = threadIdx.x, w = t >> 6, l = t & 63;
  const int tile = blockIdx.x*4 + w;          // 0..511
  short8v ah0, ah1, al0, al1;
  {
    const size_t b = (size_t)tile*6;
    ah0 = *(const short8v*)&Saf[((b+0)*64 + l)*8];
    ah1 = *(const short8v*)&Saf[((b+1)*64 + l)*8];
    al0 = *(const short8v*)&Saf[((b+4)*64 + l)*8];
    al1 = *(const short8v*)&Saf[((b+5)*64 + l)*8];
  }
  const int row0 = tile*16 + (l >> 4)*4;
  const int c16 = l & 15;
  #pragma unroll
  for (int m = 0; m < 4; ++m) {
    const unsigned short* G = (m==0) ? Gu1 : (m==1) ? Gc1 : (m==2) ? Gu2 : Gc2;
    float* outp = (m==0) ? u1 : (m==1) ? c1 : (m==2) ? u2 : c2;
    #pragma unroll
    for (int nt = 0; nt < 4; ++nt) {
      const unsigned short* p = G + (size_t)nt*6*64*8;
      short8v wh0 = *(const short8v*)&p[(0*64 + l)*8];
      short8v wh1 = *(const short8v*)&p[(1*64 + l)*8];
      short8v wl0 = *(const short8v*)&p[(2*64 + l)*8];
      short8v wl1 = *(const short8v*)&p[(3*64 + l)*8];
      f32x4 acc = {0.f, 0.f, 0.f, 0.f};
      acc = __builtin_amdgcn_mfma_f32_16x16x32_bf16(ah0, wh0, acc, 0, 0, 0);
      acc = __builtin_amdgcn_mfma_f32_16x16x32_bf16(ah1, wh1, acc, 0, 0, 0);
      acc = __builtin_amdgcn_mfma_f32_16x16x32_bf16(ah0, wl0, acc, 0, 0, 0);
      acc = __builtin_amdgcn_mfma_f32_16x16x32_bf16(ah1, wl1, acc, 0, 0, 0);
      acc = __builtin_amdgcn_mfma_f32_16x16x32_bf16(al0, wh0, acc, 0, 0, 0);
      acc = __builtin_amdgcn_mfma_f32_16x16x32_bf16(al1, wh1, acc, 0, 0, 0);
      const int col = nt*16 + c16;
      float bias = 0.f;
      if (m == 1) bias = bt1[col] + bp1[col];
      if (m == 3) bias = bt2[col] + bp2[col];
      #pragma unroll
      for (int r = 0; r < 4; ++r)
        outp[(size_t)(row0 + r)*64 + col] = acc[r] + bias;
    }
  }
}

#define MFMA_PAIR6(ACC, AF, BF)                                                  \
  ACC = __builtin_amdgcn_mfma_f32_16x16x32_bf16(AF[0], BF[0], ACC, 0, 0, 0);     \
  ACC = __builtin_amdgcn_mfma_f32_16x16x32_bf16(AF[1], BF[1], ACC, 0, 0, 0);     \
  ACC = __builtin_amdgcn_mfma_f32_16x16x32_bf16(AF[0], BF[2], ACC, 0, 0, 0);     \
  ACC = __builtin_amdgcn_mfma_f32_16x16x32_bf16(AF[1], BF[3], ACC, 0, 0, 0);     \
  ACC = __builtin_amdgcn_mfma_f32_16x16x32_bf16(AF[2], BF[0], ACC, 0, 0, 0);     \
  ACC = __builtin_amdgcn_mfma_f32_16x16x32_bf16(AF[3], BF[1], ACC, 0, 0, 0);

// ---------------- K2a: sampled distances (8 of 64 chunks), grid 512 ----------------
__global__ __launch_bounds__(512) void k2a_sample(
    const unsigned short* __restrict__ Saf,
    const unsigned short* __restrict__ Sbf,
    const float* __restrict__ sqf,
    float* __restrict__ sampD)
{
  const int t = threadIdx.x, w = t >> 6, l = t & 63;
  const int qb = blockIdx.x >> 1, sh = blockIdx.x & 1;
  const int qbase = qb * 32;
  short8v afr[2][4];
  #pragma unroll
  for (int mt = 0; mt < 2; ++mt) {
    const size_t b = (size_t)(qb*2 + mt)*6;
    afr[mt][0] = *(const short8v*)&Saf[((b+0)*64 + l)*8];
    afr[mt][1] = *(const short8v*)&Saf[((b+1)*64 + l)*8];
    afr[mt][2] = *(const short8v*)&Saf[((b+4)*64 + l)*8];
    afr[mt][3] = *(const short8v*)&Saf[((b+5)*64 + l)*8];
  }
  const int ncol = w*16 + (l & 15);
  for (int sl = 0; sl < 4; ++sl) {
    const int s = sh*4 + sl;
    const int cb = s*8;
    const int jbase = cb*128;
    short8v bfr[4];
    {
      const size_t b = (size_t)(cb*8 + w)*6;
      #pragma unroll
      for (int k = 0; k < 4; ++k)
        bfr[k] = *(const short8v*)&Sbf[((b+k)*64 + l)*8];
    }
    const float sc = sqf[jbase + ncol];
    f32x4 acc0 = {0.f,0.f,0.f,0.f}, acc1 = {0.f,0.f,0.f,0.f};
    MFMA_PAIR6(acc0, afr[0], bfr);
    MFMA_PAIR6(acc1, afr[1], bfr);
    #pragma unroll
    for (int r = 0; r < 4; ++r) {
      const int q0 = qbase + 0*16 + (l >> 4)*4 + r;
      const int q1 = qbase + 1*16 + (l >> 4)*4 + r;
      sampD[(size_t)q0*1024 + s*128 + ncol] = sc - 2.0f*acc0[r];
      sampD[(size_t)q1*1024 + s*128 + ncol] = sc - 2.0f*acc1[r];
    }
  }
}

// ---------------- K2t: per-query threshold = 41st-smallest of 1024 samples ----------------
__global__ __launch_bounds__(256) void k2t_threshold(
    const float* __restrict__ sampD, float* __restrict__ Tq)
{
  const int w = threadIdx.x >> 6, l = threadIdx.x & 63;
  const int q = blockIdx.x*4 + w;
  unsigned ku[16];
  #pragma unroll
  for (int k = 0; k < 16; ++k)
    ku[k] = key_of(sampD[(size_t)q*1024 + k*64 + l]);
  unsigned prefix = 0; int need = 41;
  for (int b = 31; b >= 0; --b) {
    unsigned p2 = prefix << 1;
    int c = 0;
    #pragma unroll
    for (int k = 0; k < 16; ++k) c += ((ku[k] >> b) == p2);
    #pragma unroll
    for (int off = 32; off; off >>= 1) c += __shfl_xor(c, off);
    if (c >= need) prefix = p2; else { prefix = p2 | 1u; need -= c; }
  }
  if (l == 0) Tq[q] = key_inv(prefix);
}

// ---------------- K2f: streaming filter, LDS counters, grid 512 ----------------
__global__ __launch_bounds__(512) void k2f_filter(
    const unsigned short* __restrict__ Saf,
    const unsigned short* __restrict__ Sbf,
    const float* __restrict__ sqf,
    const float* __restrict__ Tq,
    int* __restrict__ cnt_g,
    float* __restrict__ survD, int* __restrict__ survI)
{
  __shared__ int cnt_sh[32];
  const int t = threadIdx.x, w = t >> 6, l = t & 63;
  const int qb = blockIdx.x >> 1, half = blockIdx.x & 1;
  const int qbase = qb * 32;
  if (t < 32) cnt_sh[t] = 0;
  short8v afr[2][4];
  float Tr[2][4]; int qloc[2][4];
  #pragma unroll
  for (int mt = 0; mt < 2; ++mt) {
    const size_t b = (size_t)(qb*2 + mt)*6;
    afr[mt][0] = *(const short8v*)&Saf[((b+0)*64 + l)*8];
    afr[mt][1] = *(const short8v*)&Saf[((b+1)*64 + l)*8];
    afr[mt][2] = *(const short8v*)&Saf[((b+4)*64 + l)*8];
    afr[mt][3] = *(const short8v*)&Saf[((b+5)*64 + l)*8];
    #pragma unroll
    for (int r = 0; r < 4; ++r) {
      qloc[mt][r] = mt*16 + (l >> 4)*4 + r;
      Tr[mt][r] = Tq[qbase + qloc[mt][r]];
    }
  }
  short8v bfr[4];
  {
    const size_t b = (size_t)(half*256 + w)*6;
    #pragma unroll
    for (int k = 0; k < 4; ++k)
      bfr[k] = *(const short8v*)&Sbf[((b+k)*64 + l)*8];
  }
  const int ncol = w*16 + (l & 15);
  __syncthreads();
  for (int cb = 0; cb < 32; ++cb) {
    const int jbase = half*4096 + cb*128;
    const float sc = sqf[jbase + ncol];
    f32x4 acc0 = {0.f,0.f,0.f,0.f}, acc1 = {0.f,0.f,0.f,0.f};
    MFMA_PAIR6(acc0, afr[0], bfr);
    MFMA_PAIR6(acc1, afr[1], bfr);
    if (cb < 31) {
      const size_t b = (size_t)(half*256 + (cb+1)*8 + w)*6;
      #pragma unroll
      for (int k = 0; k < 4; ++k)
        bfr[k] = *(const short8v*)&Sbf[((b+k)*64 + l)*8];
    }
    const int j = jbase + ncol;
    #pragma unroll
    for (int r = 0; r < 4; ++r) {
      float d0 = sc - 2.0f*acc0[r];
      if (d0 < Tr[0][r]) {
        int slot = atomicAdd(&cnt_sh[qloc[0][r]], 1);   // LDS atomic
        if (slot < SSEG) {
          size_t base = ((size_t)(qbase + qloc[0][r])*2 + half)*SSEG + slot;
          survD[base] = d0; survI[base] = j;
        }
      }
      float d1 = sc - 2.0f*acc1[r];
      if (d1 < Tr[1][r]) {
        int slot = atomicAdd(&cnt_sh[qloc[1][r]], 1);
        if (slot < SSEG) {
          size_t base = ((size_t)(qbase + qloc[1][r])*2 + half)*SSEG + slot;
          survD[base] = d1; survI[base] = j;
        }
      }
    }
  }
  __syncthreads();
  if (t < 32) cnt_g[(qbase + t)*2 + half] = cnt_sh[t];
}

// ---------------- K2s: exact fp32 top-48 of segmented survivors ----------------
__global__ __launch_bounds__(256) void k2s_select(
    const float* __restrict__ survD, const int* __restrict__ survI,
    const int* __restrict__ cnt_g, int* __restrict__ idx48)
{
  const int w = threadIdx.x >> 6, l = threadIdx.x & 63;
  const int node = blockIdx.x*4 + w;
  const int c0 = min(cnt_g[node*2 + 0], SSEG);
  const int c1 = min(cnt_g[node*2 + 1], SSEG);
  unsigned ku[10]; int iv[10];
  #pragma unroll
  for (int k = 0; k < 10; ++k) {
    int e = k*64 + l;
    int seg = (e >= SSEG);
    int off = e - seg*SSEG;
    bool v = off < (seg ? c1 : c0);
    size_t base = ((size_t)node*2 + seg)*SSEG + off;
    float d = v ? survD[base] : 0.f;
    iv[k] = v ? survI[base] : 0;
    ku[k] = v ? key_of(d) : 0xFFFFFFFFu;
  }
  unsigned prefix = 0; int need = KSEL;
  for (int b = 31; b >= 0; --b) {
    unsigned p2 = prefix << 1;
    int c = 0;
    #pragma unroll
    for (int k = 0; k < 10; ++k) c += ((ku[k] >> b) == p2);
    #pragma unroll
    for (int off = 32; off; off >>= 1) c += __shfl_xor(c, off);
    if (c >= need) prefix = p2; else { prefix = p2 | 1u; need -= c; }
  }
  const unsigned long long below = (1ull << l) - 1ull;
  int base = 0;
  #pragma unroll
  for (int k = 0; k < 10; ++k) {
    unsigned long long blt = __ballot(ku[k] < prefix);
    if (ku[k] < prefix) {
      int pos = base + __popcll(blt & below);
      idx48[(size_t)node*KSEL + pos] = iv[k];
    }
    base += __popcll(blt);
  }
  #pragma unroll
  for (int k = 0; k < 10; ++k) {
    unsigned long long beq = __ballot(ku[k] == prefix);
    if (ku[k] == prefix) {
      int pos = base + __popcll(beq & below);
      if (pos < KSEL) idx48[(size_t)node*KSEL + pos] = iv[k];
    }
    base += __popcll(beq);
  }
}

// ---------------- K2r: fp64 exact re-rank of the 48 -> sorted idx40 ----------------
__global__ __launch_bounds__(256) void k2r_rerank(
    const double* __restrict__ f64d, const double* __restrict__ sq64,
    const int* __restrict__ idx48, int* __restrict__ idx40)
{
  __shared__ double part[KSEL][4];
  __shared__ double dist_sh[KSEL];
  __shared__ int    cand_sh[KSEL];
  const int t = threadIdx.x;
  const int node = blockIdx.x;
  if (t < KSEL) cand_sh[t] = idx48[(size_t)node*KSEL + t];
  __syncthreads();
  if (t < 192) {
    int c = t >> 2, qt = t & 3;
    int cand = cand_sh[c];
    const double* fi = f64d + (size_t)node*DD + qt*16;
    const double* fc = f64d + (size_t)cand*DD + qt*16;
    double a0 = 0.0, a1 = 0.0;
    #pragma unroll
    for (int d = 0; d < 16; d += 2) { a0 += fi[d]*fc[d]; a1 += fi[d+1]*fc[d+1]; }
    part[c][qt] = a0 + a1;
  }
  __syncthreads();
  if (t < KSEL) {
    int cand = cand_sh[t];
    dist_sh[t] = sq64[node] + sq64[cand]
               - 2.0*(part[t][0] + part[t][1] + part[t][2] + part[t][3]);
  }
  __syncthreads();
  if (t < KSEL) {
    double dm = dist_sh[t]; int cand = cand_sh[t];
    int rank = 0;
    for (int j = 0; j < KSEL; ++j) {
      double dj = dist_sh[j];
      int    ij = cand_sh[j];
      rank += (dj < dm) || (dj == dm && ij < cand);
    }
    if (rank < 40) idx40[(size_t)node*40 + rank] = cand;
  }
}

// ---------------- K3: MFMA edge-convs, hi-only bf16, 2 nodes/block ----------------
__global__ __launch_bounds__(256) void k3_edgeconv(
    const float* __restrict__ f32v,
    const float* __restrict__ u1, const float* __restrict__ c1,
    const float* __restrict__ u2, const float* __restrict__ c2,
    const unsigned short* __restrict__ F1a, const unsigned short* __restrict__ F1b,
    const unsigned short* __restrict__ F2a, const unsigned short* __restrict__ F2b,
    const float* __restrict__ bm1a, const float* __restrict__ bm1b,
    const float* __restrict__ bm2a, const float* __restrict__ bm2b,
    const int* __restrict__ idx40, float* __restrict__ hout)
{
  __shared__ unsigned short au16[2][32*72];   // a as bf16, row stride 72
  __shared__ float red_s[2][2][64];
  __shared__ int idx_sh[80];
  const int t = threadIdx.x;
  const int w = t >> 6, l = t & 63;
  const int sub = w >> 1, mt = w & 1;
  const int i = blockIdx.x*2 + sub;
  const int row16 = l & 15;
  const int q8 = (l >> 4) << 3;
  if (t < 80) idx_sh[t] = idx40[(size_t)(blockIdx.x*2 + (t >= 40))*40 + (t >= 40 ? t - 40 : t)];
  __syncthreads();

  for (int conv = 0; conv < 2; ++conv) {
    const float* u_g = conv ? u2 : u1;
    const float* c_g = conv ? c2 : c1;
    const unsigned short* WfA = conv ? F2a : F1a;
    const unsigned short* WfB = conv ? F2b : F1b;
    const float* bav = conv ? bm2a : bm1a;
    const float* bbv = conv ? bm2b : bm1b;

    const int row = mt*16 + row16;
    const bool valid = row < 20;
    const int nb = valid ? idx_sh[sub*40 + (conv ? 2*row : row)] : idx_sh[sub*40];
    short8v fr0, fr1;
    {
      const float* up = u_g + (size_t)nb*DD;
      const float* cp = c_g + (size_t)i*DD;
      float4 ua = *(const float4*)&up[q8];
      float4 ub = *(const float4*)&up[q8 + 4];
      float4 uc = *(const float4*)&up[32 + q8];
      float4 ud = *(const float4*)&up[32 + q8 + 4];
      float4 ca = *(const float4*)&cp[q8];
      float4 cb = *(const float4*)&cp[q8 + 4];
      float4 cc = *(const float4*)&cp[32 + q8];
      float4 cd = *(const float4*)&cp[32 + q8 + 4];
      float z0[8] = {ca.x-ua.x, ca.y-ua.y, ca.z-ua.z, ca.w-ua.w,
                     cb.x-ub.x, cb.y-ub.y, cb.z-ub.z, cb.w-ub.w};
      float z1[8] = {cc.x-uc.x, cc.y-uc.y, cc.z-uc.z, cc.w-uc.w,
                     cd.x-ud.x, cd.y-ud.y, cd.z-ud.z, cd.w-ud.w};
      union { unsigned short us[8]; short8v v; } h0, h1;
      #pragma unroll
      for (int j = 0; j < 8; ++j) {
        float x0 = valid ? LEAKY(z0[j]) : 0.f;
        float x1 = valid ? LEAKY(z1[j]) : 0.f;
        h0.us[j] = f2bf(x0);
        h1.us[j] = f2bf(x1);
      }
      fr0 = h0.v; fr1 = h1.v;
    }
    f32x4 acc[4] = {{0,0,0,0},{0,0,0,0},{0,0,0,0},{0,0,0,0}};
    #pragma unroll
    for (int nt = 0; nt < 4; ++nt) {
      const unsigned short* p = WfA + (size_t)nt*6*64*8;
      short8v w0 = *(const short8v*)&p[(0*64 + l)*8];
      short8v w1 = *(const short8v*)&p[(1*64 + l)*8];
      acc[nt] = __builtin_amdgcn_mfma_f32_16x16x32_bf16(fr0, w0, acc[nt], 0, 0, 0);
      acc[nt] = __builtin_amdgcn_mfma_f32_16x16x32_bf16(fr1, w1, acc[nt], 0, 0, 0);
    }
    #pragma unroll
    for (int nt = 0; nt < 4; ++nt) {
      const int col = nt*16 + row16;
      const float ba = bav[col];
      #pragma unroll
      for (int r = 0; r < 4; ++r) {
        const int arow = mt*16 + (l >> 4)*4 + r;
        float v = acc[nt][r] + ba; v = LEAKY(v);
        au16[sub][arow*72 + col] = f2bf(v);
      }
    }
    __syncthreads();
    short8v g0, g1;
    {
      const unsigned short* base = &au16[sub][(mt*16 + row16)*72 + q8];
      g0 = *(const short8v*)&base[0];
      g1 = *(const short8v*)&base[32];
    }
    f32x4 bacc[4] = {{0,0,0,0},{0,0,0,0},{0,0,0,0},{0,0,0,0}};
    #pragma unroll
    for (int nt = 0; nt < 4; ++nt) {
      const unsigned short* p = WfB + (size_t)nt*6*64*8;
      short8v w0 = *(const short8v*)&p[(0*64 + l)*8];
      short8v w1 = *(const short8v*)&p[(1*64 + l)*8];
      bacc[nt] = __builtin_amdgcn_mfma_f32_16x16x32_bf16(g0, w0, bacc[nt], 0, 0, 0);
      bacc[nt] = __builtin_amdgcn_mfma_f32_16x16x32_bf16(g1, w1, bacc[nt], 0, 0, 0);
    }
    #pragma unroll
    for (int nt = 0; nt < 4; ++nt) {
      const int col = nt*16 + row16;
      const float bb2 = bbv[col];
      float m = -__builtin_inff();
      #pragma unroll
      for (int r = 0; r < 4; ++r) {
        const int arow = mt*16 + (l >> 4)*4 + r;
        if (arow < 20) m = fmaxf(m, bacc[nt][r] + bb2);
      }
      m = fmaxf(m, __shfl_xor(m, 16));
      m = fmaxf(m, __shfl_xor(m, 32));
      if ((l >> 4) == 0) red_s[sub][mt][col] = m;
    }
    __syncthreads();
    if (t < 128) {
      int s2 = t >> 6, col = t & 63;
      hout[(size_t)(blockIdx.x*2 + s2)*192 + conv*64 + col] =
          fmaxf(red_s[s2][0][col], red_s[s2][1][col]);
    }
    __syncthreads();
  }
  if (t < 128) {
    int s2 = t >> 6, col = t & 63;
    float m = -__builtin_inff();
    #pragma unroll
    for (int k = 0; k < 9; ++k)
      m = fmaxf(m, f32v[(size_t)idx_sh[s2*40 + k]*DD + col]);
    hout[(size_t)(blockIdx.x*2 + s2)*192 + 128 + col] = m;
  }
}

// ---------------- K4: final linear + bias + residual ----------------
__global__ __launch_bounds__(256) void k4_final(
    const float* __restrict__ hbuf, const float* __restrict__ WlT,
    const float* __restrict__ bl, const float* __restrict__ feature,
    float* __restrict__ out)
{
  __shared__ __align__(16) float h_sh[16*192];
  const int t = threadIdx.x;
  const int nbase = blockIdx.x * 16;
  #pragma unroll
  for (int r = 0; r < 3; ++r) {
    int flat = t + 256*r;
    int n = flat / 48, j4 = flat % 48;
    *(float4*)&h_sh[n*192 + 4*j4] = *(const float4*)&hbuf[(nbase+n)*192 + 4*j4];
  }
  __syncthreads();
  float acc[16];
  #pragma unroll
  for (int n = 0; n < 16; ++n) acc[n] = 0.f;
  for (int j4 = 0; j4 < 48; ++j4) {
    float w0 = WlT[(4*j4+0)*256 + t];
    float w1 = WlT[(4*j4+1)*256 + t];
    float w2 = WlT[(4*j4+2)*256 + t];
    float w3 = WlT[(4*j4+3)*256 + t];
    #pragma unroll
    for (int n = 0; n < 16; ++n) {
      float4 hv = *(const float4*)&h_sh[n*192 + 4*j4];
      acc[n] += hv.x*w0 + hv.y*w1 + hv.z*w2 + hv.w*w3;
    }
  }
  float blv = bl[t];
  #pragma unroll
  for (int n = 0; n < 16; ++n)
    out[(nbase+n)*256 + t] = acc[n] + blv + feature[(nbase+n)*256 + t];
}

extern "C" void kernel_launch(void* const* d_in, const int* in_sizes, int n_in,
                              void* d_out, int out_size, void* d_ws, size_t ws_size,
                              hipStream_t stream) {
  const float* feature = (const float*)d_in[0];
  const float* Wb   = (const float*)d_in[1];
  const float* bb   = (const float*)d_in[2];
  const float* Wt1  = (const float*)d_in[3];
  const float* bt1  = (const float*)d_in[4];
  const float* Wp1  = (const float*)d_in[5];
  const float* bp1  = (const float*)d_in[6];
  const float* Wm1a = (const float*)d_in[7];
  const float* bm1a = (const float*)d_in[8];
  const float* Wm1b = (const float*)d_in[9];
  const float* bm1b = (const float*)d_in[10];
  const float* Wt2  = (const float*)d_in[11];
  const float* bt2  = (const float*)d_in[12];
  const float* Wp2  = (const float*)d_in[13];
  const float* bp2  = (const float*)d_in[14];
  const float* Wm2a = (const float*)d_in[15];
  const float* bm2a = (const float*)d_in[16];
  const float* Wm2b = (const float*)d_in[17];
  const float* bm2b = (const float*)d_in[18];
  const float* Wl   = (const float*)d_in[19];
  const float* bl   = (const float*)d_in[20];
  float* out = (float*)d_out;

  char* ws = (char*)d_ws;
  double* f64d = (double*)(ws + 0);
  double* sq64 = (double*)(ws + 4194304);
  float*  f32v = (float*)(ws + 4259840);
  float*  sqf  = (float*)(ws + 6356992);
  float*  u1   = (float*)(ws + 6389760);
  float*  c1   = (float*)(ws + 8486912);
  float*  u2   = (float*)(ws + 10584064);
  float*  c2   = (float*)(ws + 12681216);
  int*    idx48= (int*)(ws + 14778368);
  int*    idx40= (int*)(ws + 16351232);
  float*  hbuf = (float*)(ws + 17661952);
  float*  WlT  = (float*)(ws + 23953408);
  unsigned short* Saf = (unsigned short*)(ws + 24150016);
  unsigned short* Sbf = (unsigned short*)(ws + 27295744);
  float*  WbT  = (float*)(ws + 30441472);
  unsigned short* F1a = (unsigned short*)(ws + 30572544);
  unsigned short* F1b = (unsigned short*)(ws + 30597120);
  unsigned short* F2a = (unsigned short*)(ws + 30621696);
  unsigned short* F2b = (unsigned short*)(ws + 30646272);
  float*  Tq   = (float*)(ws + 30670848);
  int*    cnt_g= (int*)(ws + 30703616);
  float*  survD= (float*)(ws + 30769152);
  int*    survI= (int*)(ws + 51740672);
  float*  sampD= (float*)(ws + 30769152);   // aliases surv (dead before k2f)
  // G fragment buffers alias f64d region (f64d dead after k2r; k1c/k1d run after)
  unsigned short* Gu1 = (unsigned short*)(ws + 0);
  unsigned short* Gc1 = (unsigned short*)(ws + 24576);
  unsigned short* Gu2 = (unsigned short*)(ws + 49152);
  unsigned short* Gc2 = (unsigned short*)(ws + 73728);

  hipLaunchKernelGGL(k0_prep, dim3(256), dim3(256), 0, stream, Wl, Wb, WlT, WbT);
  hipLaunchKernelGGL(k1a_f64, dim3(1024), dim3(512), 0, stream,
                     feature, WbT, bb, f64d, sq64, f32v, sqf);
  hipLaunchKernelGGL(k1b_frag, dim3(768), dim3(256), 0, stream, f32v, Saf, Sbf);
  hipLaunchKernelGGL(k2a_sample, dim3(512), dim3(512), 0, stream, Saf, Sbf, sqf, sampD);
  hipLaunchKernelGGL(k2t_threshold, dim3(2048), dim3(256), 0, stream, sampD, Tq);
  hipLaunchKernelGGL(k2f_filter, dim3(512), dim3(512), 0, stream,
                     Saf, Sbf, sqf, Tq, cnt_g, survD, survI);
  hipLaunchKernelGGL(k2s_select, dim3(2048), dim3(256), 0, stream, survD, survI, cnt_g, idx48);
  hipLaunchKernelGGL(k2r_rerank, dim3(8192), dim3(256), 0, stream, f64d, sq64, idx48, idx40);
  hipLaunchKernelGGL(k1c_wfrag, dim3(48), dim3(256), 0, stream,
                     Wm1a, Wm1b, Wm2a, Wm2b, Wt1, Wp1, Wt2, Wp2,
                     F1a, F1b, F2a, F2b, Gu1, Gc1, Gu2, Gc2);
  hipLaunchKernelGGL(k1d_uc, dim3(128), dim3(256), 0, stream,
                     Saf, Gu1, Gc1, Gu2, Gc2, bt1, bp1, bt2, bp2, u1, c1, u2, c2);
  hipLaunchKernelGGL(k3_edgeconv, dim3(4096), dim3(256), 0, stream,
                     f32v, u1, c1, u2, c2, F1a, F1b, F2a, F2b,
                     bm1a, bm1b, bm2a, bm2b, idx40, hbuf);
  hipLaunchKernelGGL(k4_final, dim3(512), dim3(256), 0, stream, hbuf, WlT, bl, feature, out);
}

// Round 14
// 377.390 us; speedup vs baseline: 1.1463x; 1.0035x over previous
//
#include <hip/hip_runtime.h>
#include <math.h>

#define NPT   8192
#define FIN   256
#define DD    64
#define KSEL  48
#define SSEG  320

#define LEAKY(x) (((x) >= 0.f) ? (x) : 0.01f*(x))

using short8v = __attribute__((ext_vector_type(8))) short;
using f32x4   = __attribute__((ext_vector_type(4))) float;

__device__ inline unsigned short f2bf(float x) {
  union { float f; unsigned u; } v; v.f = x;
  unsigned r = v.u + 0x7fff + ((v.u >> 16) & 1);   // RNE
  return (unsigned short)(r >> 16);
}
__device__ inline float bf2f(unsigned short h) {
  union { unsigned u; float f; } v; v.u = ((unsigned)h) << 16; return v.f;
}
__device__ inline unsigned key_of(float f) {
  unsigned u = __float_as_uint(f);
  return (u & 0x80000000u) ? ~u : (u | 0x80000000u);
}
__device__ inline float key_inv(unsigned k) {
  unsigned u = (k >> 31) ? (k ^ 0x80000000u) : ~k;
  return __uint_as_float(u);
}

// ---------------- K0: transposes (Wl, Wb only) ----------------
__global__ void k0_prep(const float* __restrict__ Wl, const float* __restrict__ Wb,
                        float* __restrict__ WlT, float* __restrict__ WbT)
{
  const int b = blockIdx.x, t = threadIdx.x;
  if (b < 192) {
    WlT[b*256 + t] = Wl[t*192 + b];
  } else {
    int j = (b - 192)*4 + (t >> 6), o = t & 63;
    WbT[j*64 + o] = Wb[o*256 + j];
  }
}

// ---------------- K1a: f (fp64) via LDS-staged WbT ----------------
__global__ __launch_bounds__(512) void k1a_f64(
    const float* __restrict__ feature, const float* __restrict__ WbT,
    const float* __restrict__ bb,
    double* __restrict__ f64d, double* __restrict__ sq64,
    float* __restrict__ f32v, float* __restrict__ sqf)
{
  __shared__ __align__(16) float4 Q[64*64];   // 64 KB
  const int t = threadIdx.x, w = t >> 6, l = t & 63;
  const int i = blockIdx.x*8 + w;
  #pragma unroll
  for (int r = 0; r < 8; ++r) {
    int flat = t + 512*r;
    int jj = flat >> 6, col = flat & 63;
    float4 q;
    q.x = WbT[(4*jj+0)*64 + col];
    q.y = WbT[(4*jj+1)*64 + col];
    q.z = WbT[(4*jj+2)*64 + col];
    q.w = WbT[(4*jj+3)*64 + col];
    Q[jj*64 + col] = q;
  }
  __syncthreads();
  const float* frow = feature + (size_t)i*FIN;
  double a0 = (double)bb[l], a1 = 0.0, a2 = 0.0, a3 = 0.0;
  #pragma unroll 4
  for (int jj = 0; jj < 64; ++jj) {
    float4 fv = *(const float4*)&frow[4*jj];
    float4 q = Q[jj*64 + l];
    a0 += (double)fv.x * (double)q.x;
    a1 += (double)fv.y * (double)q.y;
    a2 += (double)fv.z * (double)q.z;
    a3 += (double)fv.w * (double)q.w;
  }
  double facc = (a0 + a1) + (a2 + a3);
  f64d[(size_t)i*DD + l] = facc;
  float f32 = (float)facc;
  f32v[(size_t)i*DD + l] = f32;
  double s = facc*facc;
  #pragma unroll
  for (int off = 32; off; off >>= 1) s += __shfl_xor(s, off);
  if (l == 0) { sq64[i] = s; sqf[i] = (float)s; }
}

// ---------------- K1b: MFMA fragments for KNN (bf16 hi/lo) ----------------
__global__ __launch_bounds__(256) void k1b_frag(
    const float* __restrict__ f32v,
    unsigned short* __restrict__ Saf, unsigned short* __restrict__ Sbf)
{
  const int w = threadIdx.x >> 6, l = threadIdx.x & 63;
  const int task = blockIdx.x*4 + w;          // 0..3071
  const int tile = task / 6, ks = task % 6;
  const int row  = tile*16 + (l & 15);
  const int inner = (ks & 1)*32 + ((l >> 4) << 3);
  union { unsigned short u[8]; short8v v; } pa, pb;
  #pragma unroll
  for (int j = 0; j < 8; ++j) {
    float x = f32v[row*64 + inner + j];
    unsigned short hi = f2bf(x);
    unsigned short lo = f2bf(x - bf2f(hi));
    pa.u[j] = (ks < 4) ? hi : lo;
    pb.u[j] = (ks < 2) ? hi : ((ks < 4) ? lo : hi);
  }
  size_t off = ((size_t)(tile*6 + ks)*64 + l)*8;
  *(short8v*)&Saf[off] = pa.v;
  *(short8v*)&Sbf[off] = pb.v;
}

// ---------------- K1c: weight B-fragments (8 mats, runs after k2r) ----------------
__global__ __launch_bounds__(256) void k1c_wfrag(
    const float* __restrict__ Wm1a, const float* __restrict__ Wm1b,
    const float* __restrict__ Wm2a, const float* __restrict__ Wm2b,
    const float* __restrict__ Wt1, const float* __restrict__ Wp1,
    const float* __restrict__ Wt2, const float* __restrict__ Wp2,
    unsigned short* __restrict__ F1a, unsigned short* __restrict__ F1b,
    unsigned short* __restrict__ F2a, unsigned short* __restrict__ F2b,
    unsigned short* __restrict__ Gu1, unsigned short* __restrict__ Gc1,
    unsigned short* __restrict__ Gu2, unsigned short* __restrict__ Gc2)
{
  const int w = threadIdx.x >> 6, l = threadIdx.x & 63;
  const int task = blockIdx.x*4 + w;          // 0..191
  const int which = task / 24, rem = task % 24;
  const int nt = rem / 6, ks = rem % 6;
  const float* W  = (which==0) ? Wm1a : (which==1) ? Wm1b : (which==2) ? Wm2a :
                    (which==3) ? Wm2b : (which==4) ? Wt1  : (which==5) ? Wt1  :
                    (which==6) ? Wt2  : Wt2;
  const float* W2 = (which==5) ? Wp1 : (which==7) ? Wp2 : (const float*)0;
  unsigned short* F = (which==0) ? F1a : (which==1) ? F1b : (which==2) ? F2a :
                      (which==3) ? F2b : (which==4) ? Gu1 : (which==5) ? Gc1 :
                      (which==6) ? Gu2 : Gc2;
  const int row = nt*16 + (l & 15);
  const int inner = (ks & 1)*32 + ((l >> 4) << 3);
  union { unsigned short u[8]; short8v v; } p;
  #pragma unroll
  for (int j = 0; j < 8; ++j) {
    float x = W[row*64 + inner + j];
    if (W2) x += W2[row*64 + inner + j];
    unsigned short hi = f2bf(x);
    unsigned short lo = f2bf(x - bf2f(hi));
    p.u[j] = (ks < 2) ? hi : ((ks < 4) ? lo : hi);
  }
  *(short8v*)&F[((size_t)(nt*6 + ks)*64 + l)*8] = p.v;
}

// ---------------- K1d: u/c via MFMA (hi/lo 3-term) ----------------
__global__ __launch_bounds__(256) void k1d_uc(
    const unsigned short* __restrict__ Saf,
    const unsigned short* __restrict__ Gu1, const unsigned short* __restrict__ Gc1,
    const unsigned short* __restrict__ Gu2, const unsigned short* __restrict__ Gc2,
    const float* __restrict__ bt1, const float* __restrict__ bp1,
    const float* __restrict__ bt2, const float* __restrict__ bp2,
    float* __restrict__ u1, float* __restrict__ c1,
    float* __restrict__ u2, float* __restrict__ c2)
{
  const int t = threadIdx.x, w = t >> 6, l = t & 63;
  const int tile = blockIdx.x*4 + w;          // 0..511
  short8v ah0, ah1, al0, al1;
  {
    const size_t b = (size_t)tile*6;
    ah0 = *(const short8v*)&Saf[((b+0)*64 + l)*8];
    ah1 = *(const short8v*)&Saf[((b+1)*64 + l)*8];
    al0 = *(const short8v*)&Saf[((b+4)*64 + l)*8];
    al1 = *(const short8v*)&Saf[((b+5)*64 + l)*8];
  }
  const int row0 = tile*16 + (l >> 4)*4;
  const int c16 = l & 15;
  #pragma unroll
  for (int m = 0; m < 4; ++m) {
    const unsigned short* G = (m==0) ? Gu1 : (m==1) ? Gc1 : (m==2) ? Gu2 : Gc2;
    float* outp = (m==0) ? u1 : (m==1) ? c1 : (m==2) ? u2 : c2;
    #pragma unroll
    for (int nt = 0; nt < 4; ++nt) {
      const unsigned short* p = G + (size_t)nt*6*64*8;
      short8v wh0 = *(const short8v*)&p[(0*64 + l)*8];
      short8v wh1 = *(const short8v*)&p[(1*64 + l)*8];
      short8v wl0 = *(const short8v*)&p[(2*64 + l)*8];
      short8v wl1 = *(const short8v*)&p[(3*64 + l)*8];
      f32x4 acc = {0.f, 0.f, 0.f, 0.f};
      acc = __builtin_amdgcn_mfma_f32_16x16x32_bf16(ah0, wh0, acc, 0, 0, 0);
      acc = __builtin_amdgcn_mfma_f32_16x16x32_bf16(ah1, wh1, acc, 0, 0, 0);
      acc = __builtin_amdgcn_mfma_f32_16x16x32_bf16(ah0, wl0, acc, 0, 0, 0);
      acc = __builtin_amdgcn_mfma_f32_16x16x32_bf16(ah1, wl1, acc, 0, 0, 0);
      acc = __builtin_amdgcn_mfma_f32_16x16x32_bf16(al0, wh0, acc, 0, 0, 0);
      acc = __builtin_amdgcn_mfma_f32_16x16x32_bf16(al1, wh1, acc, 0, 0, 0);
      const int col = nt*16 + c16;
      float bias = 0.f;
      if (m == 1) bias = bt1[col] + bp1[col];
      if (m == 3) bias = bt2[col] + bp2[col];
      #pragma unroll
      for (int r = 0; r < 4; ++r)
        outp[(size_t)(row0 + r)*64 + col] = acc[r] + bias;
    }
  }
}

#define MFMA_PAIR6(ACC, AF, BF)                                                  \
  ACC = __builtin_amdgcn_mfma_f32_16x16x32_bf16(AF[0], BF[0], ACC, 0, 0, 0);     \
  ACC = __builtin_amdgcn_mfma_f32_16x16x32_bf16(AF[1], BF[1], ACC, 0, 0, 0);     \
  ACC = __builtin_amdgcn_mfma_f32_16x16x32_bf16(AF[0], BF[2], ACC, 0, 0, 0);     \
  ACC = __builtin_amdgcn_mfma_f32_16x16x32_bf16(AF[1], BF[3], ACC, 0, 0, 0);     \
  ACC = __builtin_amdgcn_mfma_f32_16x16x32_bf16(AF[2], BF[0], ACC, 0, 0, 0);     \
  ACC = __builtin_amdgcn_mfma_f32_16x16x32_bf16(AF[3], BF[1], ACC, 0, 0, 0);

// ---------------- K2a: sampled distances (8 of 64 chunks), grid 512 ----------------
__global__ __launch_bounds__(512) void k2a_sample(
    const unsigned short* __restrict__ Saf,
    const unsigned short* __restrict__ Sbf,
    const float* __restrict__ sqf,
    float* __restrict__ sampD)
{
  const int t = threadIdx.x, w = t >> 6, l = t & 63;
  const int qb = blockIdx.x >> 1, sh = blockIdx.x & 1;
  const int qbase = qb * 32;
  short8v afr[2][4];
  #pragma unroll
  for (int mt = 0; mt < 2; ++mt) {
    const size_t b = (size_t)(qb*2 + mt)*6;
    afr[mt][0] = *(const short8v*)&Saf[((b+0)*64 + l)*8];
    afr[mt][1] = *(const short8v*)&Saf[((b+1)*64 + l)*8];
    afr[mt][2] = *(const short8v*)&Saf[((b+4)*64 + l)*8];
    afr[mt][3] = *(const short8v*)&Saf[((b+5)*64 + l)*8];
  }
  const int ncol = w*16 + (l & 15);
  for (int sl = 0; sl < 4; ++sl) {
    const int s = sh*4 + sl;
    const int cb = s*8;
    const int jbase = cb*128;
    short8v bfr[4];
    {
      const size_t b = (size_t)(cb*8 + w)*6;
      #pragma unroll
      for (int k = 0; k < 4; ++k)
        bfr[k] = *(const short8v*)&Sbf[((b+k)*64 + l)*8];
    }
    const float sc = sqf[jbase + ncol];
    f32x4 acc0 = {0.f,0.f,0.f,0.f}, acc1 = {0.f,0.f,0.f,0.f};
    MFMA_PAIR6(acc0, afr[0], bfr);
    MFMA_PAIR6(acc1, afr[1], bfr);
    #pragma unroll
    for (int r = 0; r < 4; ++r) {
      const int q0 = qbase + 0*16 + (l >> 4)*4 + r;
      const int q1 = qbase + 1*16 + (l >> 4)*4 + r;
      sampD[(size_t)q0*1024 + s*128 + ncol] = sc - 2.0f*acc0[r];
      sampD[(size_t)q1*1024 + s*128 + ncol] = sc - 2.0f*acc1[r];
    }
  }
}

// ---------------- K2t: per-query threshold = 41st-smallest of 1024 samples ----------------
__global__ __launch_bounds__(256) void k2t_threshold(
    const float* __restrict__ sampD, float* __restrict__ Tq)
{
  const int w = threadIdx.x >> 6, l = threadIdx.x & 63;
  const int q = blockIdx.x*4 + w;
  unsigned ku[16];
  #pragma unroll
  for (int k = 0; k < 16; ++k)
    ku[k] = key_of(sampD[(size_t)q*1024 + k*64 + l]);
  unsigned prefix = 0; int need = 41;
  for (int b = 31; b >= 0; --b) {
    unsigned p2 = prefix << 1;
    int c = 0;
    #pragma unroll
    for (int k = 0; k < 16; ++k) c += ((ku[k] >> b) == p2);
    #pragma unroll
    for (int off = 32; off; off >>= 1) c += __shfl_xor(c, off);
    if (c >= need) prefix = p2; else { prefix = p2 | 1u; need -= c; }
  }
  if (l == 0) Tq[q] = key_inv(prefix);
}

// ---------------- K2f: streaming filter, LDS counters, grid 512 ----------------
__global__ __launch_bounds__(512) void k2f_filter(
    const unsigned short* __restrict__ Saf,
    const unsigned short* __restrict__ Sbf,
    const float* __restrict__ sqf,
    const float* __restrict__ Tq,
    int* __restrict__ cnt_g,
    float* __restrict__ survD, int* __restrict__ survI)
{
  __shared__ int cnt_sh[32];
  const int t = threadIdx.x, w = t >> 6, l = t & 63;
  const int qb = blockIdx.x >> 1, half = blockIdx.x & 1;
  const int qbase = qb * 32;
  if (t < 32) cnt_sh[t] = 0;
  short8v afr[2][4];
  float Tr[2][4]; int qloc[2][4];
  #pragma unroll
  for (int mt = 0; mt < 2; ++mt) {
    const size_t b = (size_t)(qb*2 + mt)*6;
    afr[mt][0] = *(const short8v*)&Saf[((b+0)*64 + l)*8];
    afr[mt][1] = *(const short8v*)&Saf[((b+1)*64 + l)*8];
    afr[mt][2] = *(const short8v*)&Saf[((b+4)*64 + l)*8];
    afr[mt][3] = *(const short8v*)&Saf[((b+5)*64 + l)*8];
    #pragma unroll
    for (int r = 0; r < 4; ++r) {
      qloc[mt][r] = mt*16 + (l >> 4)*4 + r;
      Tr[mt][r] = Tq[qbase + qloc[mt][r]];
    }
  }
  short8v bfr[4];
  {
    const size_t b = (size_t)(half*256 + w)*6;
    #pragma unroll
    for (int k = 0; k < 4; ++k)
      bfr[k] = *(const short8v*)&Sbf[((b+k)*64 + l)*8];
  }
  const int ncol = w*16 + (l & 15);
  __syncthreads();
  for (int cb = 0; cb < 32; ++cb) {
    const int jbase = half*4096 + cb*128;
    const float sc = sqf[jbase + ncol];
    f32x4 acc0 = {0.f,0.f,0.f,0.f}, acc1 = {0.f,0.f,0.f,0.f};
    MFMA_PAIR6(acc0, afr[0], bfr);
    MFMA_PAIR6(acc1, afr[1], bfr);
    if (cb < 31) {
      const size_t b = (size_t)(half*256 + (cb+1)*8 + w)*6;
      #pragma unroll
      for (int k = 0; k < 4; ++k)
        bfr[k] = *(const short8v*)&Sbf[((b+k)*64 + l)*8];
    }
    const int j = jbase + ncol;
    #pragma unroll
    for (int r = 0; r < 4; ++r) {
      float d0 = sc - 2.0f*acc0[r];
      if (d0 < Tr[0][r]) {
        int slot = atomicAdd(&cnt_sh[qloc[0][r]], 1);   // LDS atomic
        if (slot < SSEG) {
          size_t base = ((size_t)(qbase + qloc[0][r])*2 + half)*SSEG + slot;
          survD[base] = d0; survI[base] = j;
        }
      }
      float d1 = sc - 2.0f*acc1[r];
      if (d1 < Tr[1][r]) {
        int slot = atomicAdd(&cnt_sh[qloc[1][r]], 1);
        if (slot < SSEG) {
          size_t base = ((size_t)(qbase + qloc[1][r])*2 + half)*SSEG + slot;
          survD[base] = d1; survI[base] = j;
        }
      }
    }
  }
  __syncthreads();
  if (t < 32) cnt_g[(qbase + t)*2 + half] = cnt_sh[t];
}

// ---------------- K2s: exact fp32 top-48 of segmented survivors ----------------
__global__ __launch_bounds__(256) void k2s_select(
    const float* __restrict__ survD, const int* __restrict__ survI,
    const int* __restrict__ cnt_g, int* __restrict__ idx48)
{
  const int w = threadIdx.x >> 6, l = threadIdx.x & 63;
  const int node = blockIdx.x*4 + w;
  const int c0 = min(cnt_g[node*2 + 0], SSEG);
  const int c1 = min(cnt_g[node*2 + 1], SSEG);
  unsigned ku[10]; int iv[10];
  #pragma unroll
  for (int k = 0; k < 10; ++k) {
    int e = k*64 + l;
    int seg = (e >= SSEG);
    int off = e - seg*SSEG;
    bool v = off < (seg ? c1 : c0);
    size_t base = ((size_t)node*2 + seg)*SSEG + off;
    float d = v ? survD[base] : 0.f;
    iv[k] = v ? survI[base] : 0;
    ku[k] = v ? key_of(d) : 0xFFFFFFFFu;
  }
  unsigned prefix = 0; int need = KSEL;
  for (int b = 31; b >= 0; --b) {
    unsigned p2 = prefix << 1;
    int c = 0;
    #pragma unroll
    for (int k = 0; k < 10; ++k) c += ((ku[k] >> b) == p2);
    #pragma unroll
    for (int off = 32; off; off >>= 1) c += __shfl_xor(c, off);
    if (c >= need) prefix = p2; else { prefix = p2 | 1u; need -= c; }
  }
  const unsigned long long below = (1ull << l) - 1ull;
  int base = 0;
  #pragma unroll
  for (int k = 0; k < 10; ++k) {
    unsigned long long blt = __ballot(ku[k] < prefix);
    if (ku[k] < prefix) {
      int pos = base + __popcll(blt & below);
      idx48[(size_t)node*KSEL + pos] = iv[k];
    }
    base += __popcll(blt);
  }
  #pragma unroll
  for (int k = 0; k < 10; ++k) {
    unsigned long long beq = __ballot(ku[k] == prefix);
    if (ku[k] == prefix) {
      int pos = base + __popcll(beq & below);
      if (pos < KSEL) idx48[(size_t)node*KSEL + pos] = iv[k];
    }
    base += __popcll(beq);
  }
}

// ---------------- K2r: fp64 re-rank, LDS-staged coalesced gather ----------------
__global__ __launch_bounds__(256) void k2r_rerank(
    const double* __restrict__ f64d, const double* __restrict__ sq64,
    const int* __restrict__ idx48, int* __restrict__ idx40)
{
  __shared__ double cands[KSEL*65];   // stride 65 to break bank alignment
  __shared__ double frow[64];
  __shared__ double part[KSEL][4];
  __shared__ double dist_sh[KSEL];
  __shared__ int    cand_sh[KSEL];
  const int t = threadIdx.x;
  const int node = blockIdx.x;
  if (t < KSEL) cand_sh[t] = idx48[(size_t)node*KSEL + t];
  if (t >= 192) frow[t - 192] = f64d[(size_t)node*DD + (t - 192)];
  __syncthreads();
  // stage 48 candidate rows: wave reads one full row per iter (coalesced 512 B)
  {
    const int w = t >> 6, l = t & 63;
    #pragma unroll
    for (int r = 0; r < 12; ++r) {
      const int c = w + 4*r;
      cands[c*65 + l] = f64d[(size_t)cand_sh[c]*DD + l];
    }
  }
  __syncthreads();
  if (t < 192) {
    const int c = t >> 2, qt = t & 3;
    const double* cp = &cands[c*65 + qt*16];
    const double* fp = &frow[qt*16];
    double a0 = 0.0, a1 = 0.0;
    #pragma unroll
    for (int d = 0; d < 16; d += 2) { a0 += fp[d]*cp[d]; a1 += fp[d+1]*cp[d+1]; }
    part[c][qt] = a0 + a1;
  }
  __syncthreads();
  if (t < KSEL) {
    int cand = cand_sh[t];
    dist_sh[t] = sq64[node] + sq64[cand]
               - 2.0*(part[t][0] + part[t][1] + part[t][2] + part[t][3]);
  }
  __syncthreads();
  if (t < KSEL) {
    double dm = dist_sh[t]; int cand = cand_sh[t];
    int rank = 0;
    for (int j = 0; j < KSEL; ++j) {
      double dj = dist_sh[j];
      int    ij = cand_sh[j];
      rank += (dj < dm) || (dj == dm && ij < cand);
    }
    if (rank < 40) idx40[(size_t)node*40 + rank] = cand;
  }
}

// ---------------- K3: MFMA edge-convs, hi-only bf16, 2 nodes/block ----------------
__global__ __launch_bounds__(256) void k3_edgeconv(
    const float* __restrict__ f32v,
    const float* __restrict__ u1, const float* __restrict__ c1,
    const float* __restrict__ u2, const float* __restrict__ c2,
    const unsigned short* __restrict__ F1a, const unsigned short* __restrict__ F1b,
    const unsigned short* __restrict__ F2a, const unsigned short* __restrict__ F2b,
    const float* __restrict__ bm1a, const float* __restrict__ bm1b,
    const float* __restrict__ bm2a, const float* __restrict__ bm2b,
    const int* __restrict__ idx40, float* __restrict__ hout)
{
  __shared__ unsigned short au16[2][32*72];   // a as bf16, row stride 72
  __shared__ float red_s[2][2][64];
  __shared__ int idx_sh[80];
  const int t = threadIdx.x;
  const int w = t >> 6, l = t & 63;
  const int sub = w >> 1, mt = w & 1;
  const int i = blockIdx.x*2 + sub;
  const int row16 = l & 15;
  const int q8 = (l >> 4) << 3;
  if (t < 80) idx_sh[t] = idx40[(size_t)(blockIdx.x*2 + (t >= 40))*40 + (t >= 40 ? t - 40 : t)];
  __syncthreads();

  for (int conv = 0; conv < 2; ++conv) {
    const float* u_g = conv ? u2 : u1;
    const float* c_g = conv ? c2 : c1;
    const unsigned short* WfA = conv ? F2a : F1a;
    const unsigned short* WfB = conv ? F2b : F1b;
    const float* bav = conv ? bm2a : bm1a;
    const float* bbv = conv ? bm2b : bm1b;

    const int row = mt*16 + row16;
    const bool valid = row < 20;
    const int nb = valid ? idx_sh[sub*40 + (conv ? 2*row : row)] : idx_sh[sub*40];
    short8v fr0, fr1;
    {
      const float* up = u_g + (size_t)nb*DD;
      const float* cp = c_g + (size_t)i*DD;
      float4 ua = *(const float4*)&up[q8];
      float4 ub = *(const float4*)&up[q8 + 4];
      float4 uc = *(const float4*)&up[32 + q8];
      float4 ud = *(const float4*)&up[32 + q8 + 4];
      float4 ca = *(const float4*)&cp[q8];
      float4 cb = *(const float4*)&cp[q8 + 4];
      float4 cc = *(const float4*)&cp[32 + q8];
      float4 cd = *(const float4*)&cp[32 + q8 + 4];
      float z0[8] = {ca.x-ua.x, ca.y-ua.y, ca.z-ua.z, ca.w-ua.w,
                     cb.x-ub.x, cb.y-ub.y, cb.z-ub.z, cb.w-ub.w};
      float z1[8] = {cc.x-uc.x, cc.y-uc.y, cc.z-uc.z, cc.w-uc.w,
                     cd.x-ud.x, cd.y-ud.y, cd.z-ud.z, cd.w-ud.w};
      union { unsigned short us[8]; short8v v; } h0, h1;
      #pragma unroll
      for (int j = 0; j < 8; ++j) {
        float x0 = valid ? LEAKY(z0[j]) : 0.f;
        float x1 = valid ? LEAKY(z1[j]) : 0.f;
        h0.us[j] = f2bf(x0);
        h1.us[j] = f2bf(x1);
      }
      fr0 = h0.v; fr1 = h1.v;
    }
    f32x4 acc[4] = {{0,0,0,0},{0,0,0,0},{0,0,0,0},{0,0,0,0}};
    #pragma unroll
    for (int nt = 0; nt < 4; ++nt) {
      const unsigned short* p = WfA + (size_t)nt*6*64*8;
      short8v w0 = *(const short8v*)&p[(0*64 + l)*8];
      short8v w1 = *(const short8v*)&p[(1*64 + l)*8];
      acc[nt] = __builtin_amdgcn_mfma_f32_16x16x32_bf16(fr0, w0, acc[nt], 0, 0, 0);
      acc[nt] = __builtin_amdgcn_mfma_f32_16x16x32_bf16(fr1, w1, acc[nt], 0, 0, 0);
    }
    #pragma unroll
    for (int nt = 0; nt < 4; ++nt) {
      const int col = nt*16 + row16;
      const float ba = bav[col];
      #pragma unroll
      for (int r = 0; r < 4; ++r) {
        const int arow = mt*16 + (l >> 4)*4 + r;
        float v = acc[nt][r] + ba; v = LEAKY(v);
        au16[sub][arow*72 + col] = f2bf(v);
      }
    }
    __syncthreads();
    short8v g0, g1;
    {
      const unsigned short* base = &au16[sub][(mt*16 + row16)*72 + q8];
      g0 = *(const short8v*)&base[0];
      g1 = *(const short8v*)&base[32];
    }
    f32x4 bacc[4] = {{0,0,0,0},{0,0,0,0},{0,0,0,0},{0,0,0,0}};
    #pragma unroll
    for (int nt = 0; nt < 4; ++nt) {
      const unsigned short* p = WfB + (size_t)nt*6*64*8;
      short8v w0 = *(const short8v*)&p[(0*64 + l)*8];
      short8v w1 = *(const short8v*)&p[(1*64 + l)*8];
      bacc[nt] = __builtin_amdgcn_mfma_f32_16x16x32_bf16(g0, w0, bacc[nt], 0, 0, 0);
      bacc[nt] = __builtin_amdgcn_mfma_f32_16x16x32_bf16(g1, w1, bacc[nt], 0, 0, 0);
    }
    #pragma unroll
    for (int nt = 0; nt < 4; ++nt) {
      const int col = nt*16 + row16;
      const float bb2 = bbv[col];
      float m = -__builtin_inff();
      #pragma unroll
      for (int r = 0; r < 4; ++r) {
        const int arow = mt*16 + (l >> 4)*4 + r;
        if (arow < 20) m = fmaxf(m, bacc[nt][r] + bb2);
      }
      m = fmaxf(m, __shfl_xor(m, 16));
      m = fmaxf(m, __shfl_xor(m, 32));
      if ((l >> 4) == 0) red_s[sub][mt][col] = m;
    }
    __syncthreads();
    if (t < 128) {
      int s2 = t >> 6, col = t & 63;
      hout[(size_t)(blockIdx.x*2 + s2)*192 + conv*64 + col] =
          fmaxf(red_s[s2][0][col], red_s[s2][1][col]);
    }
    __syncthreads();
  }
  if (t < 128) {
    int s2 = t >> 6, col = t & 63;
    float m = -__builtin_inff();
    #pragma unroll
    for (int k = 0; k < 9; ++k)
      m = fmaxf(m, f32v[(size_t)idx_sh[s2*40 + k]*DD + col]);
    hout[(size_t)(blockIdx.x*2 + s2)*192 + 128 + col] = m;
  }
}

// ---------------- K4: final linear + bias + residual ----------------
__global__ __launch_bounds__(256) void k4_final(
    const float* __restrict__ hbuf, const float* __restrict__ WlT,
    const float* __restrict__ bl, const float* __restrict__ feature,
    float* __restrict__ out)
{
  __shared__ __align__(16) float h_sh[16*192];
  const int t = threadIdx.x;
  const int nbase = blockIdx.x * 16;
  #pragma unroll
  for (int r = 0; r < 3; ++r) {
    int flat = t + 256*r;
    int n = flat / 48, j4 = flat % 48;
    *(float4*)&h_sh[n*192 + 4*j4] = *(const float4*)&hbuf[(nbase+n)*192 + 4*j4];
  }
  __syncthreads();
  float acc[16];
  #pragma unroll
  for (int n = 0; n < 16; ++n) acc[n] = 0.f;
  for (int j4 = 0; j4 < 48; ++j4) {
    float w0 = WlT[(4*j4+0)*256 + t];
    float w1 = WlT[(4*j4+1)*256 + t];
    float w2 = WlT[(4*j4+2)*256 + t];
    float w3 = WlT[(4*j4+3)*256 + t];
    #pragma unroll
    for (int n = 0; n < 16; ++n) {
      float4 hv = *(const float4*)&h_sh[n*192 + 4*j4];
      acc[n] += hv.x*w0 + hv.y*w1 + hv.z*w2 + hv.w*w3;
    }
  }
  float blv = bl[t];
  #pragma unroll
  for (int n = 0; n < 16; ++n)
    out[(nbase+n)*256 + t] = acc[n] + blv + feature[(nbase+n)*256 + t];
}

extern "C" void kernel_launch(void* const* d_in, const int* in_sizes, int n_in,
                              void* d_out, int out_size, void* d_ws, size_t ws_size,
                              hipStream_t stream) {
  const float* feature = (const float*)d_in[0];
  const float* Wb   = (const float*)d_in[1];
  const float* bb   = (const float*)d_in[2];
  const float* Wt1  = (const float*)d_in[3];
  const float* bt1  = (const float*)d_in[4];
  const float* Wp1  = (const float*)d_in[5];
  const float* bp1  = (const float*)d_in[6];
  const float* Wm1a = (const float*)d_in[7];
  const float* bm1a = (const float*)d_in[8];
  const float* Wm1b = (const float*)d_in[9];
  const float* bm1b = (const float*)d_in[10];
  const float* Wt2  = (const float*)d_in[11];
  const float* bt2  = (const float*)d_in[12];
  const float* Wp2  = (const float*)d_in[13];
  const float* bp2  = (const float*)d_in[14];
  const float* Wm2a = (const float*)d_in[15];
  const float* bm2a = (const float*)d_in[16];
  const float* Wm2b = (const float*)d_in[17];
  const float* bm2b = (const float*)d_in[18];
  const float* Wl   = (const float*)d_in[19];
  const float* bl   = (const float*)d_in[20];
  float* out = (float*)d_out;

  char* ws = (char*)d_ws;
  double* f64d = (double*)(ws + 0);
  double* sq64 = (double*)(ws + 4194304);
  float*  f32v = (float*)(ws + 4259840);
  float*  sqf  = (float*)(ws + 6356992);
  float*  u1   = (float*)(ws + 6389760);
  float*  c1   = (float*)(ws + 8486912);
  float*  u2   = (float*)(ws + 10584064);
  float*  c2   = (float*)(ws + 12681216);
  int*    idx48= (int*)(ws + 14778368);
  int*    idx40= (int*)(ws + 16351232);
  float*  hbuf = (float*)(ws + 17661952);
  float*  WlT  = (float*)(ws + 23953408);
  unsigned short* Saf = (unsigned short*)(ws + 24150016);
  unsigned short* Sbf = (unsigned short*)(ws + 27295744);
  float*  WbT  = (float*)(ws + 30441472);
  unsigned short* F1a = (unsigned short*)(ws + 30572544);
  unsigned short* F1b = (unsigned short*)(ws + 30597120);
  unsigned short* F2a = (unsigned short*)(ws + 30621696);
  unsigned short* F2b = (unsigned short*)(ws + 30646272);
  float*  Tq   = (float*)(ws + 30670848);
  int*    cnt_g= (int*)(ws + 30703616);
  float*  survD= (float*)(ws + 30769152);
  int*    survI= (int*)(ws + 51740672);
  float*  sampD= (float*)(ws + 30769152);   // aliases surv (dead before k2f)
  // G fragment buffers alias f64d region (f64d dead after k2r; k1c/k1d run after)
  unsigned short* Gu1 = (unsigned short*)(ws + 0);
  unsigned short* Gc1 = (unsigned short*)(ws + 24576);
  unsigned short* Gu2 = (unsigned short*)(ws + 49152);
  unsigned short* Gc2 = (unsigned short*)(ws + 73728);

  hipLaunchKernelGGL(k0_prep, dim3(256), dim3(256), 0, stream, Wl, Wb, WlT, WbT);
  hipLaunchKernelGGL(k1a_f64, dim3(1024), dim3(512), 0, stream,
                     feature, WbT, bb, f64d, sq64, f32v, sqf);
  hipLaunchKernelGGL(k1b_frag, dim3(768), dim3(256), 0, stream, f32v, Saf, Sbf);
  hipLaunchKernelGGL(k2a_sample, dim3(512), dim3(512), 0, stream, Saf, Sbf, sqf, sampD);
  hipLaunchKernelGGL(k2t_threshold, dim3(2048), dim3(256), 0, stream, sampD, Tq);
  hipLaunchKernelGGL(k2f_filter, dim3(512), dim3(512), 0, stream,
                     Saf, Sbf, sqf, Tq, cnt_g, survD, survI);
  hipLaunchKernelGGL(k2s_select, dim3(2048), dim3(256), 0, stream, survD, survI, cnt_g, idx48);
  hipLaunchKernelGGL(k2r_rerank, dim3(8192), dim3(256), 0, stream, f64d, sq64, idx48, idx40);
  hipLaunchKernelGGL(k1c_wfrag, dim3(48), dim3(256), 0, stream,
                     Wm1a, Wm1b, Wm2a, Wm2b, Wt1, Wp1, Wt2, Wp2,
                     F1a, F1b, F2a, F2b, Gu1, Gc1, Gu2, Gc2);
  hipLaunchKernelGGL(k1d_uc, dim3(128), dim3(256), 0, stream,
                     Saf, Gu1, Gc1, Gu2, Gc2, bt1, bp1, bt2, bp2, u1, c1, u2, c2);
  hipLaunchKernelGGL(k3_edgeconv, dim3(4096), dim3(256), 0, stream,
                     f32v, u1, c1, u2, c2, F1a, F1b, F2a, F2b,
                     bm1a, bm1b, bm2a, bm2b, idx40, hbuf);
  hipLaunchKernelGGL(k4_final, dim3(512), dim3(256), 0, stream, hbuf, WlT, bl, feature, out);
}

// Round 15
// 372.346 us; speedup vs baseline: 1.1618x; 1.0135x over previous
//
#include <hip/hip_runtime.h>
#include <math.h>

#define NPT   8192
#define FIN   256
#define DD    64
#define KSEL  48
#define SSEG  320

#define LEAKY(x) (((x) >= 0.f) ? (x) : 0.01f*(x))

using short8v = __attribute__((ext_vector_type(8))) short;
using f32x4   = __attribute__((ext_vector_type(4))) float;

__device__ inline unsigned short f2bf(float x) {
  union { float f; unsigned u; } v; v.f = x;
  unsigned r = v.u + 0x7fff + ((v.u >> 16) & 1);   // RNE
  return (unsigned short)(r >> 16);
}
__device__ inline float bf2f(unsigned short h) {
  union { unsigned u; float f; } v; v.u = ((unsigned)h) << 16; return v.f;
}
__device__ inline unsigned key_of(float f) {
  unsigned u = __float_as_uint(f);
  return (u & 0x80000000u) ? ~u : (u | 0x80000000u);
}
__device__ inline float key_inv(unsigned k) {
  unsigned u = (k >> 31) ? (k ^ 0x80000000u) : ~k;
  return __uint_as_float(u);
}

// ---------------- K0: transposes (Wl, Wb only) ----------------
__global__ void k0_prep(const float* __restrict__ Wl, const float* __restrict__ Wb,
                        float* __restrict__ WlT, float* __restrict__ WbT)
{
  const int b = blockIdx.x, t = threadIdx.x;
  if (b < 192) {
    WlT[b*256 + t] = Wl[t*192 + b];
  } else {
    int j = (b - 192)*4 + (t >> 6), o = t & 63;
    WbT[j*64 + o] = Wb[o*256 + j];
  }
}

// ---------------- K1a: f (fp64) via LDS-staged WbT ----------------
__global__ __launch_bounds__(512) void k1a_f64(
    const float* __restrict__ feature, const float* __restrict__ WbT,
    const float* __restrict__ bb,
    double* __restrict__ f64d, double* __restrict__ sq64,
    float* __restrict__ f32v, float* __restrict__ sqf)
{
  __shared__ __align__(16) float4 Q[64*64];   // 64 KB
  const int t = threadIdx.x, w = t >> 6, l = t & 63;
  const int i = blockIdx.x*8 + w;
  #pragma unroll
  for (int r = 0; r < 8; ++r) {
    int flat = t + 512*r;
    int jj = flat >> 6, col = flat & 63;
    float4 q;
    q.x = WbT[(4*jj+0)*64 + col];
    q.y = WbT[(4*jj+1)*64 + col];
    q.z = WbT[(4*jj+2)*64 + col];
    q.w = WbT[(4*jj+3)*64 + col];
    Q[jj*64 + col] = q;
  }
  __syncthreads();
  const float* frow = feature + (size_t)i*FIN;
  double a0 = (double)bb[l], a1 = 0.0, a2 = 0.0, a3 = 0.0;
  #pragma unroll 4
  for (int jj = 0; jj < 64; ++jj) {
    float4 fv = *(const float4*)&frow[4*jj];
    float4 q = Q[jj*64 + l];
    a0 += (double)fv.x * (double)q.x;
    a1 += (double)fv.y * (double)q.y;
    a2 += (double)fv.z * (double)q.z;
    a3 += (double)fv.w * (double)q.w;
  }
  double facc = (a0 + a1) + (a2 + a3);
  f64d[(size_t)i*DD + l] = facc;
  float f32 = (float)facc;
  f32v[(size_t)i*DD + l] = f32;
  double s = facc*facc;
  #pragma unroll
  for (int off = 32; off; off >>= 1) s += __shfl_xor(s, off);
  if (l == 0) { sq64[i] = s; sqf[i] = (float)s; }
}

// ---------------- K1b: MFMA fragments for KNN (bf16 hi/lo) ----------------
__global__ __launch_bounds__(256) void k1b_frag(
    const float* __restrict__ f32v,
    unsigned short* __restrict__ Saf, unsigned short* __restrict__ Sbf)
{
  const int w = threadIdx.x >> 6, l = threadIdx.x & 63;
  const int task = blockIdx.x*4 + w;          // 0..3071
  const int tile = task / 6, ks = task % 6;
  const int row  = tile*16 + (l & 15);
  const int inner = (ks & 1)*32 + ((l >> 4) << 3);
  union { unsigned short u[8]; short8v v; } pa, pb;
  #pragma unroll
  for (int j = 0; j < 8; ++j) {
    float x = f32v[row*64 + inner + j];
    unsigned short hi = f2bf(x);
    unsigned short lo = f2bf(x - bf2f(hi));
    pa.u[j] = (ks < 4) ? hi : lo;
    pb.u[j] = (ks < 2) ? hi : ((ks < 4) ? lo : hi);
  }
  size_t off = ((size_t)(tile*6 + ks)*64 + l)*8;
  *(short8v*)&Saf[off] = pa.v;
  *(short8v*)&Sbf[off] = pb.v;
}

// ---------------- K1c: weight B-fragments (8 mats, runs after k2r) ----------------
__global__ __launch_bounds__(256) void k1c_wfrag(
    const float* __restrict__ Wm1a, const float* __restrict__ Wm1b,
    const float* __restrict__ Wm2a, const float* __restrict__ Wm2b,
    const float* __restrict__ Wt1, const float* __restrict__ Wp1,
    const float* __restrict__ Wt2, const float* __restrict__ Wp2,
    unsigned short* __restrict__ F1a, unsigned short* __restrict__ F1b,
    unsigned short* __restrict__ F2a, unsigned short* __restrict__ F2b,
    unsigned short* __restrict__ Gu1, unsigned short* __restrict__ Gc1,
    unsigned short* __restrict__ Gu2, unsigned short* __restrict__ Gc2)
{
  const int w = threadIdx.x >> 6, l = threadIdx.x & 63;
  const int task = blockIdx.x*4 + w;          // 0..191
  const int which = task / 24, rem = task % 24;
  const int nt = rem / 6, ks = rem % 6;
  const float* W  = (which==0) ? Wm1a : (which==1) ? Wm1b : (which==2) ? Wm2a :
                    (which==3) ? Wm2b : (which==4) ? Wt1  : (which==5) ? Wt1  :
                    (which==6) ? Wt2  : Wt2;
  const float* W2 = (which==5) ? Wp1 : (which==7) ? Wp2 : (const float*)0;
  unsigned short* F = (which==0) ? F1a : (which==1) ? F1b : (which==2) ? F2a :
                      (which==3) ? F2b : (which==4) ? Gu1 : (which==5) ? Gc1 :
                      (which==6) ? Gu2 : Gc2;
  const int row = nt*16 + (l & 15);
  const int inner = (ks & 1)*32 + ((l >> 4) << 3);
  union { unsigned short u[8]; short8v v; } p;
  #pragma unroll
  for (int j = 0; j < 8; ++j) {
    float x = W[row*64 + inner + j];
    if (W2) x += W2[row*64 + inner + j];
    unsigned short hi = f2bf(x);
    unsigned short lo = f2bf(x - bf2f(hi));
    p.u[j] = (ks < 2) ? hi : ((ks < 4) ? lo : hi);
  }
  *(short8v*)&F[((size_t)(nt*6 + ks)*64 + l)*8] = p.v;
}

// ---------------- K1d: u/c via MFMA (hi/lo 3-term) ----------------
__global__ __launch_bounds__(256) void k1d_uc(
    const unsigned short* __restrict__ Saf,
    const unsigned short* __restrict__ Gu1, const unsigned short* __restrict__ Gc1,
    const unsigned short* __restrict__ Gu2, const unsigned short* __restrict__ Gc2,
    const float* __restrict__ bt1, const float* __restrict__ bp1,
    const float* __restrict__ bt2, const float* __restrict__ bp2,
    float* __restrict__ u1, float* __restrict__ c1,
    float* __restrict__ u2, float* __restrict__ c2)
{
  const int t = threadIdx.x, w = t >> 6, l = t & 63;
  const int tile = blockIdx.x*4 + w;          // 0..511
  short8v ah0, ah1, al0, al1;
  {
    const size_t b = (size_t)tile*6;
    ah0 = *(const short8v*)&Saf[((b+0)*64 + l)*8];
    ah1 = *(const short8v*)&Saf[((b+1)*64 + l)*8];
    al0 = *(const short8v*)&Saf[((b+4)*64 + l)*8];
    al1 = *(const short8v*)&Saf[((b+5)*64 + l)*8];
  }
  const int row0 = tile*16 + (l >> 4)*4;
  const int c16 = l & 15;
  #pragma unroll
  for (int m = 0; m < 4; ++m) {
    const unsigned short* G = (m==0) ? Gu1 : (m==1) ? Gc1 : (m==2) ? Gu2 : Gc2;
    float* outp = (m==0) ? u1 : (m==1) ? c1 : (m==2) ? u2 : c2;
    #pragma unroll
    for (int nt = 0; nt < 4; ++nt) {
      const unsigned short* p = G + (size_t)nt*6*64*8;
      short8v wh0 = *(const short8v*)&p[(0*64 + l)*8];
      short8v wh1 = *(const short8v*)&p[(1*64 + l)*8];
      short8v wl0 = *(const short8v*)&p[(2*64 + l)*8];
      short8v wl1 = *(const short8v*)&p[(3*64 + l)*8];
      f32x4 acc = {0.f, 0.f, 0.f, 0.f};
      acc = __builtin_amdgcn_mfma_f32_16x16x32_bf16(ah0, wh0, acc, 0, 0, 0);
      acc = __builtin_amdgcn_mfma_f32_16x16x32_bf16(ah1, wh1, acc, 0, 0, 0);
      acc = __builtin_amdgcn_mfma_f32_16x16x32_bf16(ah0, wl0, acc, 0, 0, 0);
      acc = __builtin_amdgcn_mfma_f32_16x16x32_bf16(ah1, wl1, acc, 0, 0, 0);
      acc = __builtin_amdgcn_mfma_f32_16x16x32_bf16(al0, wh0, acc, 0, 0, 0);
      acc = __builtin_amdgcn_mfma_f32_16x16x32_bf16(al1, wh1, acc, 0, 0, 0);
      const int col = nt*16 + c16;
      float bias = 0.f;
      if (m == 1) bias = bt1[col] + bp1[col];
      if (m == 3) bias = bt2[col] + bp2[col];
      #pragma unroll
      for (int r = 0; r < 4; ++r)
        outp[(size_t)(row0 + r)*64 + col] = acc[r] + bias;
    }
  }
}

#define MFMA_PAIR6(ACC, AF, BF)                                                  \
  ACC = __builtin_amdgcn_mfma_f32_16x16x32_bf16(AF[0], BF[0], ACC, 0, 0, 0);     \
  ACC = __builtin_amdgcn_mfma_f32_16x16x32_bf16(AF[1], BF[1], ACC, 0, 0, 0);     \
  ACC = __builtin_amdgcn_mfma_f32_16x16x32_bf16(AF[0], BF[2], ACC, 0, 0, 0);     \
  ACC = __builtin_amdgcn_mfma_f32_16x16x32_bf16(AF[1], BF[3], ACC, 0, 0, 0);     \
  ACC = __builtin_amdgcn_mfma_f32_16x16x32_bf16(AF[2], BF[0], ACC, 0, 0, 0);     \
  ACC = __builtin_amdgcn_mfma_f32_16x16x32_bf16(AF[3], BF[1], ACC, 0, 0, 0);

// ---------------- K2a: sampled distances (8 of 64 chunks), grid 512 ----------------
__global__ __launch_bounds__(512) void k2a_sample(
    const unsigned short* __restrict__ Saf,
    const unsigned short* __restrict__ Sbf,
    const float* __restrict__ sqf,
    float* __restrict__ sampD)
{
  const int t = threadIdx.x, w = t >> 6, l = t & 63;
  const int qb = blockIdx.x >> 1, sh = blockIdx.x & 1;
  const int qbase = qb * 32;
  short8v afr[2][4];
  #pragma unroll
  for (int mt = 0; mt < 2; ++mt) {
    const size_t b = (size_t)(qb*2 + mt)*6;
    afr[mt][0] = *(const short8v*)&Saf[((b+0)*64 + l)*8];
    afr[mt][1] = *(const short8v*)&Saf[((b+1)*64 + l)*8];
    afr[mt][2] = *(const short8v*)&Saf[((b+4)*64 + l)*8];
    afr[mt][3] = *(const short8v*)&Saf[((b+5)*64 + l)*8];
  }
  const int ncol = w*16 + (l & 15);
  for (int sl = 0; sl < 4; ++sl) {
    const int s = sh*4 + sl;
    const int cb = s*8;
    const int jbase = cb*128;
    short8v bfr[4];
    {
      const size_t b = (size_t)(cb*8 + w)*6;
      #pragma unroll
      for (int k = 0; k < 4; ++k)
        bfr[k] = *(const short8v*)&Sbf[((b+k)*64 + l)*8];
    }
    const float sc = sqf[jbase + ncol];
    f32x4 acc0 = {0.f,0.f,0.f,0.f}, acc1 = {0.f,0.f,0.f,0.f};
    MFMA_PAIR6(acc0, afr[0], bfr);
    MFMA_PAIR6(acc1, afr[1], bfr);
    #pragma unroll
    for (int r = 0; r < 4; ++r) {
      const int q0 = qbase + 0*16 + (l >> 4)*4 + r;
      const int q1 = qbase + 1*16 + (l >> 4)*4 + r;
      sampD[(size_t)q0*1024 + s*128 + ncol] = sc - 2.0f*acc0[r];
      sampD[(size_t)q1*1024 + s*128 + ncol] = sc - 2.0f*acc1[r];
    }
  }
}

// ---------------- K2t: per-query threshold = 41st-smallest of 1024 samples ----------------
__global__ __launch_bounds__(256) void k2t_threshold(
    const float* __restrict__ sampD, float* __restrict__ Tq)
{
  const int w = threadIdx.x >> 6, l = threadIdx.x & 63;
  const int q = blockIdx.x*4 + w;
  unsigned ku[16];
  #pragma unroll
  for (int k = 0; k < 16; ++k)
    ku[k] = key_of(sampD[(size_t)q*1024 + k*64 + l]);
  unsigned prefix = 0; int need = 41;
  for (int b = 31; b >= 0; --b) {
    unsigned p2 = prefix << 1;
    int c = 0;
    #pragma unroll
    for (int k = 0; k < 16; ++k) c += ((ku[k] >> b) == p2);
    #pragma unroll
    for (int off = 32; off; off >>= 1) c += __shfl_xor(c, off);
    if (c >= need) prefix = p2; else { prefix = p2 | 1u; need -= c; }
  }
  if (l == 0) Tq[q] = key_inv(prefix);
}

// ---------------- K2f: streaming filter, LDS counters, grid 512 ----------------
__global__ __launch_bounds__(512) void k2f_filter(
    const unsigned short* __restrict__ Saf,
    const unsigned short* __restrict__ Sbf,
    const float* __restrict__ sqf,
    const float* __restrict__ Tq,
    int* __restrict__ cnt_g,
    float* __restrict__ survD, int* __restrict__ survI)
{
  __shared__ int cnt_sh[32];
  const int t = threadIdx.x, w = t >> 6, l = t & 63;
  const int qb = blockIdx.x >> 1, half = blockIdx.x & 1;
  const int qbase = qb * 32;
  if (t < 32) cnt_sh[t] = 0;
  short8v afr[2][4];
  float Tr[2][4]; int qloc[2][4];
  #pragma unroll
  for (int mt = 0; mt < 2; ++mt) {
    const size_t b = (size_t)(qb*2 + mt)*6;
    afr[mt][0] = *(const short8v*)&Saf[((b+0)*64 + l)*8];
    afr[mt][1] = *(const short8v*)&Saf[((b+1)*64 + l)*8];
    afr[mt][2] = *(const short8v*)&Saf[((b+4)*64 + l)*8];
    afr[mt][3] = *(const short8v*)&Saf[((b+5)*64 + l)*8];
    #pragma unroll
    for (int r = 0; r < 4; ++r) {
      qloc[mt][r] = mt*16 + (l >> 4)*4 + r;
      Tr[mt][r] = Tq[qbase + qloc[mt][r]];
    }
  }
  short8v bfr[4];
  {
    const size_t b = (size_t)(half*256 + w)*6;
    #pragma unroll
    for (int k = 0; k < 4; ++k)
      bfr[k] = *(const short8v*)&Sbf[((b+k)*64 + l)*8];
  }
  const int ncol = w*16 + (l & 15);
  __syncthreads();
  for (int cb = 0; cb < 32; ++cb) {
    const int jbase = half*4096 + cb*128;
    const float sc = sqf[jbase + ncol];
    f32x4 acc0 = {0.f,0.f,0.f,0.f}, acc1 = {0.f,0.f,0.f,0.f};
    MFMA_PAIR6(acc0, afr[0], bfr);
    MFMA_PAIR6(acc1, afr[1], bfr);
    if (cb < 31) {
      const size_t b = (size_t)(half*256 + (cb+1)*8 + w)*6;
      #pragma unroll
      for (int k = 0; k < 4; ++k)
        bfr[k] = *(const short8v*)&Sbf[((b+k)*64 + l)*8];
    }
    const int j = jbase + ncol;
    #pragma unroll
    for (int r = 0; r < 4; ++r) {
      float d0 = sc - 2.0f*acc0[r];
      if (d0 < Tr[0][r]) {
        int slot = atomicAdd(&cnt_sh[qloc[0][r]], 1);   // LDS atomic
        if (slot < SSEG) {
          size_t base = ((size_t)(qbase + qloc[0][r])*2 + half)*SSEG + slot;
          survD[base] = d0; survI[base] = j;
        }
      }
      float d1 = sc - 2.0f*acc1[r];
      if (d1 < Tr[1][r]) {
        int slot = atomicAdd(&cnt_sh[qloc[1][r]], 1);
        if (slot < SSEG) {
          size_t base = ((size_t)(qbase + qloc[1][r])*2 + half)*SSEG + slot;
          survD[base] = d1; survI[base] = j;
        }
      }
    }
  }
  __syncthreads();
  if (t < 32) cnt_g[(qbase + t)*2 + half] = cnt_sh[t];
}

// ---------------- K2s: exact fp32 top-48 of segmented survivors ----------------
__global__ __launch_bounds__(256) void k2s_select(
    const float* __restrict__ survD, const int* __restrict__ survI,
    const int* __restrict__ cnt_g, int* __restrict__ idx48)
{
  const int w = threadIdx.x >> 6, l = threadIdx.x & 63;
  const int node = blockIdx.x*4 + w;
  const int c0 = min(cnt_g[node*2 + 0], SSEG);
  const int c1 = min(cnt_g[node*2 + 1], SSEG);
  unsigned ku[10]; int iv[10];
  #pragma unroll
  for (int k = 0; k < 10; ++k) {
    int e = k*64 + l;
    int seg = (e >= SSEG);
    int off = e - seg*SSEG;
    bool v = off < (seg ? c1 : c0);
    size_t base = ((size_t)node*2 + seg)*SSEG + off;
    float d = v ? survD[base] : 0.f;
    iv[k] = v ? survI[base] : 0;
    ku[k] = v ? key_of(d) : 0xFFFFFFFFu;
  }
  unsigned prefix = 0; int need = KSEL;
  for (int b = 31; b >= 0; --b) {
    unsigned p2 = prefix << 1;
    int c = 0;
    #pragma unroll
    for (int k = 0; k < 10; ++k) c += ((ku[k] >> b) == p2);
    #pragma unroll
    for (int off = 32; off; off >>= 1) c += __shfl_xor(c, off);
    if (c >= need) prefix = p2; else { prefix = p2 | 1u; need -= c; }
  }
  const unsigned long long below = (1ull << l) - 1ull;
  int base = 0;
  #pragma unroll
  for (int k = 0; k < 10; ++k) {
    unsigned long long blt = __ballot(ku[k] < prefix);
    if (ku[k] < prefix) {
      int pos = base + __popcll(blt & below);
      idx48[(size_t)node*KSEL + pos] = iv[k];
    }
    base += __popcll(blt);
  }
  #pragma unroll
  for (int k = 0; k < 10; ++k) {
    unsigned long long beq = __ballot(ku[k] == prefix);
    if (ku[k] == prefix) {
      int pos = base + __popcll(beq & below);
      if (pos < KSEL) idx48[(size_t)node*KSEL + pos] = iv[k];
    }
    base += __popcll(beq);
  }
}

// ---------------- K2r: fp64 re-rank, register-resident, 1 barrier ----------------
// Wave w owns candidates 12w..12w+11 end-to-end: coalesced row load (lane=elem),
// quarter shfl_xor reduction, partials to 2KB LDS, one barrier, dist+rank.
__global__ __launch_bounds__(256) void k2r_rerank(
    const double* __restrict__ f64d, const double* __restrict__ sq64,
    const int* __restrict__ idx48, int* __restrict__ idx40)
{
  __shared__ double part[KSEL][4];
  __shared__ double dist_sh[KSEL];
  __shared__ int    cand_sh[KSEL];
  const int t = threadIdx.x, w = t >> 6, l = t & 63;
  const int node = blockIdx.x;
  int cidx = (l < KSEL) ? idx48[(size_t)node*KSEL + l] : 0;
  if (w == 0 && l < KSEL) cand_sh[l] = cidx;
  const double fe = f64d[(size_t)node*DD + l];   // own row element
  double x[12];
  #pragma unroll
  for (int r = 0; r < 12; ++r) {
    int cr = __shfl(cidx, w*12 + r);
    x[r] = f64d[(size_t)cr*DD + l];
  }
  #pragma unroll
  for (int r = 0; r < 12; ++r) {
    double p = fe * x[r];
    p += __shfl_xor(p, 1);
    p += __shfl_xor(p, 2);
    p += __shfl_xor(p, 4);
    p += __shfl_xor(p, 8);
    if ((l & 15) == 0) part[w*12 + r][l >> 4] = p;
  }
  __syncthreads();
  if (t < KSEL) {
    int cand = cand_sh[t];
    dist_sh[t] = sq64[node] + sq64[cand]
               - 2.0*(part[t][0] + part[t][1] + part[t][2] + part[t][3]);
  }
  __syncthreads();
  if (t < KSEL) {
    double dm = dist_sh[t]; int cand = cand_sh[t];
    int rank = 0;
    for (int j = 0; j < KSEL; ++j) {
      double dj = dist_sh[j];
      int    ij = cand_sh[j];
      rank += (dj < dm) || (dj == dm && ij < cand);
    }
    if (rank < 40) idx40[(size_t)node*40 + rank] = cand;
  }
}

// ---------------- K3: MFMA edge-convs, hi-only bf16, 2 nodes/block ----------------
__global__ __launch_bounds__(256) void k3_edgeconv(
    const float* __restrict__ f32v,
    const float* __restrict__ u1, const float* __restrict__ c1,
    const float* __restrict__ u2, const float* __restrict__ c2,
    const unsigned short* __restrict__ F1a, const unsigned short* __restrict__ F1b,
    const unsigned short* __restrict__ F2a, const unsigned short* __restrict__ F2b,
    const float* __restrict__ bm1a, const float* __restrict__ bm1b,
    const float* __restrict__ bm2a, const float* __restrict__ bm2b,
    const int* __restrict__ idx40, float* __restrict__ hout)
{
  __shared__ unsigned short au16[2][32*72];   // a as bf16, row stride 72
  __shared__ float red_s[2][2][64];
  __shared__ int idx_sh[80];
  const int t = threadIdx.x;
  const int w = t >> 6, l = t & 63;
  const int sub = w >> 1, mt = w & 1;
  const int i = blockIdx.x*2 + sub;
  const int row16 = l & 15;
  const int q8 = (l >> 4) << 3;
  if (t < 80) idx_sh[t] = idx40[(size_t)(blockIdx.x*2 + (t >= 40))*40 + (t >= 40 ? t - 40 : t)];
  __syncthreads();

  for (int conv = 0; conv < 2; ++conv) {
    const float* u_g = conv ? u2 : u1;
    const float* c_g = conv ? c2 : c1;
    const unsigned short* WfA = conv ? F2a : F1a;
    const unsigned short* WfB = conv ? F2b : F1b;
    const float* bav = conv ? bm2a : bm1a;
    const float* bbv = conv ? bm2b : bm1b;

    const int row = mt*16 + row16;
    const bool valid = row < 20;
    const int nb = valid ? idx_sh[sub*40 + (conv ? 2*row : row)] : idx_sh[sub*40];
    short8v fr0, fr1;
    {
      const float* up = u_g + (size_t)nb*DD;
      const float* cp = c_g + (size_t)i*DD;
      float4 ua = *(const float4*)&up[q8];
      float4 ub = *(const float4*)&up[q8 + 4];
      float4 uc = *(const float4*)&up[32 + q8];
      float4 ud = *(const float4*)&up[32 + q8 + 4];
      float4 ca = *(const float4*)&cp[q8];
      float4 cb = *(const float4*)&cp[q8 + 4];
      float4 cc = *(const float4*)&cp[32 + q8];
      float4 cd = *(const float4*)&cp[32 + q8 + 4];
      float z0[8] = {ca.x-ua.x, ca.y-ua.y, ca.z-ua.z, ca.w-ua.w,
                     cb.x-ub.x, cb.y-ub.y, cb.z-ub.z, cb.w-ub.w};
      float z1[8] = {cc.x-uc.x, cc.y-uc.y, cc.z-uc.z, cc.w-uc.w,
                     cd.x-ud.x, cd.y-ud.y, cd.z-ud.z, cd.w-ud.w};
      union { unsigned short us[8]; short8v v; } h0, h1;
      #pragma unroll
      for (int j = 0; j < 8; ++j) {
        float x0 = valid ? LEAKY(z0[j]) : 0.f;
        float x1 = valid ? LEAKY(z1[j]) : 0.f;
        h0.us[j] = f2bf(x0);
        h1.us[j] = f2bf(x1);
      }
      fr0 = h0.v; fr1 = h1.v;
    }
    f32x4 acc[4] = {{0,0,0,0},{0,0,0,0},{0,0,0,0},{0,0,0,0}};
    #pragma unroll
    for (int nt = 0; nt < 4; ++nt) {
      const unsigned short* p = WfA + (size_t)nt*6*64*8;
      short8v w0 = *(const short8v*)&p[(0*64 + l)*8];
      short8v w1 = *(const short8v*)&p[(1*64 + l)*8];
      acc[nt] = __builtin_amdgcn_mfma_f32_16x16x32_bf16(fr0, w0, acc[nt], 0, 0, 0);
      acc[nt] = __builtin_amdgcn_mfma_f32_16x16x32_bf16(fr1, w1, acc[nt], 0, 0, 0);
    }
    #pragma unroll
    for (int nt = 0; nt < 4; ++nt) {
      const int col = nt*16 + row16;
      const float ba = bav[col];
      #pragma unroll
      for (int r = 0; r < 4; ++r) {
        const int arow = mt*16 + (l >> 4)*4 + r;
        float v = acc[nt][r] + ba; v = LEAKY(v);
        au16[sub][arow*72 + col] = f2bf(v);
      }
    }
    __syncthreads();
    short8v g0, g1;
    {
      const unsigned short* base = &au16[sub][(mt*16 + row16)*72 + q8];
      g0 = *(const short8v*)&base[0];
      g1 = *(const short8v*)&base[32];
    }
    f32x4 bacc[4] = {{0,0,0,0},{0,0,0,0},{0,0,0,0},{0,0,0,0}};
    #pragma unroll
    for (int nt = 0; nt < 4; ++nt) {
      const unsigned short* p = WfB + (size_t)nt*6*64*8;
      short8v w0 = *(const short8v*)&p[(0*64 + l)*8];
      short8v w1 = *(const short8v*)&p[(1*64 + l)*8];
      bacc[nt] = __builtin_amdgcn_mfma_f32_16x16x32_bf16(g0, w0, bacc[nt], 0, 0, 0);
      bacc[nt] = __builtin_amdgcn_mfma_f32_16x16x32_bf16(g1, w1, bacc[nt], 0, 0, 0);
    }
    #pragma unroll
    for (int nt = 0; nt < 4; ++nt) {
      const int col = nt*16 + row16;
      const float bb2 = bbv[col];
      float m = -__builtin_inff();
      #pragma unroll
      for (int r = 0; r < 4; ++r) {
        const int arow = mt*16 + (l >> 4)*4 + r;
        if (arow < 20) m = fmaxf(m, bacc[nt][r] + bb2);
      }
      m = fmaxf(m, __shfl_xor(m, 16));
      m = fmaxf(m, __shfl_xor(m, 32));
      if ((l >> 4) == 0) red_s[sub][mt][col] = m;
    }
    __syncthreads();
    if (t < 128) {
      int s2 = t >> 6, col = t & 63;
      hout[(size_t)(blockIdx.x*2 + s2)*192 + conv*64 + col] =
          fmaxf(red_s[s2][0][col], red_s[s2][1][col]);
    }
    __syncthreads();
  }
  if (t < 128) {
    int s2 = t >> 6, col = t & 63;
    float m = -__builtin_inff();
    #pragma unroll
    for (int k = 0; k < 9; ++k)
      m = fmaxf(m, f32v[(size_t)idx_sh[s2*40 + k]*DD + col]);
    hout[(size_t)(blockIdx.x*2 + s2)*192 + 128 + col] = m;
  }
}

// ---------------- K4: final linear + bias + residual ----------------
__global__ __launch_bounds__(256) void k4_final(
    const float* __restrict__ hbuf, const float* __restrict__ WlT,
    const float* __restrict__ bl, const float* __restrict__ feature,
    float* __restrict__ out)
{
  __shared__ __align__(16) float h_sh[16*192];
  const int t = threadIdx.x;
  const int nbase = blockIdx.x * 16;
  #pragma unroll
  for (int r = 0; r < 3; ++r) {
    int flat = t + 256*r;
    int n = flat / 48, j4 = flat % 48;
    *(float4*)&h_sh[n*192 + 4*j4] = *(const float4*)&hbuf[(nbase+n)*192 + 4*j4];
  }
  __syncthreads();
  float acc[16];
  #pragma unroll
  for (int n = 0; n < 16; ++n) acc[n] = 0.f;
  for (int j4 = 0; j4 < 48; ++j4) {
    float w0 = WlT[(4*j4+0)*256 + t];
    float w1 = WlT[(4*j4+1)*256 + t];
    float w2 = WlT[(4*j4+2)*256 + t];
    float w3 = WlT[(4*j4+3)*256 + t];
    #pragma unroll
    for (int n = 0; n < 16; ++n) {
      float4 hv = *(const float4*)&h_sh[n*192 + 4*j4];
      acc[n] += hv.x*w0 + hv.y*w1 + hv.z*w2 + hv.w*w3;
    }
  }
  float blv = bl[t];
  #pragma unroll
  for (int n = 0; n < 16; ++n)
    out[(nbase+n)*256 + t] = acc[n] + blv + feature[(nbase+n)*256 + t];
}

extern "C" void kernel_launch(void* const* d_in, const int* in_sizes, int n_in,
                              void* d_out, int out_size, void* d_ws, size_t ws_size,
                              hipStream_t stream) {
  const float* feature = (const float*)d_in[0];
  const float* Wb   = (const float*)d_in[1];
  const float* bb   = (const float*)d_in[2];
  const float* Wt1  = (const float*)d_in[3];
  const float* bt1  = (const float*)d_in[4];
  const float* Wp1  = (const float*)d_in[5];
  const float* bp1  = (const float*)d_in[6];
  const float* Wm1a = (const float*)d_in[7];
  const float* bm1a = (const float*)d_in[8];
  const float* Wm1b = (const float*)d_in[9];
  const float* bm1b = (const float*)d_in[10];
  const float* Wt2  = (const float*)d_in[11];
  const float* bt2  = (const float*)d_in[12];
  const float* Wp2  = (const float*)d_in[13];
  const float* bp2  = (const float*)d_in[14];
  const float* Wm2a = (const float*)d_in[15];
  const float* bm2a = (const float*)d_in[16];
  const float* Wm2b = (const float*)d_in[17];
  const float* bm2b = (const float*)d_in[18];
  const float* Wl   = (const float*)d_in[19];
  const float* bl   = (const float*)d_in[20];
  float* out = (float*)d_out;

  char* ws = (char*)d_ws;
  double* f64d = (double*)(ws + 0);
  double* sq64 = (double*)(ws + 4194304);
  float*  f32v = (float*)(ws + 4259840);
  float*  sqf  = (float*)(ws + 6356992);
  float*  u1   = (float*)(ws + 6389760);
  float*  c1   = (float*)(ws + 8486912);
  float*  u2   = (float*)(ws + 10584064);
  float*  c2   = (float*)(ws + 12681216);
  int*    idx48= (int*)(ws + 14778368);
  int*    idx40= (int*)(ws + 16351232);
  float*  hbuf = (float*)(ws + 17661952);
  float*  WlT  = (float*)(ws + 23953408);
  unsigned short* Saf = (unsigned short*)(ws + 24150016);
  unsigned short* Sbf = (unsigned short*)(ws + 27295744);
  float*  WbT  = (float*)(ws + 30441472);
  unsigned short* F1a = (unsigned short*)(ws + 30572544);
  unsigned short* F1b = (unsigned short*)(ws + 30597120);
  unsigned short* F2a = (unsigned short*)(ws + 30621696);
  unsigned short* F2b = (unsigned short*)(ws + 30646272);
  float*  Tq   = (float*)(ws + 30670848);
  int*    cnt_g= (int*)(ws + 30703616);
  float*  survD= (float*)(ws + 30769152);
  int*    survI= (int*)(ws + 51740672);
  float*  sampD= (float*)(ws + 30769152);   // aliases surv (dead before k2f)
  // G fragment buffers alias f64d region (f64d dead after k2r; k1c/k1d run after)
  unsigned short* Gu1 = (unsigned short*)(ws + 0);
  unsigned short* Gc1 = (unsigned short*)(ws + 24576);
  unsigned short* Gu2 = (unsigned short*)(ws + 49152);
  unsigned short* Gc2 = (unsigned short*)(ws + 73728);

  hipLaunchKernelGGL(k0_prep, dim3(256), dim3(256), 0, stream, Wl, Wb, WlT, WbT);
  hipLaunchKernelGGL(k1a_f64, dim3(1024), dim3(512), 0, stream,
                     feature, WbT, bb, f64d, sq64, f32v, sqf);
  hipLaunchKernelGGL(k1b_frag, dim3(768), dim3(256), 0, stream, f32v, Saf, Sbf);
  hipLaunchKernelGGL(k2a_sample, dim3(512), dim3(512), 0, stream, Saf, Sbf, sqf, sampD);
  hipLaunchKernelGGL(k2t_threshold, dim3(2048), dim3(256), 0, stream, sampD, Tq);
  hipLaunchKernelGGL(k2f_filter, dim3(512), dim3(512), 0, stream,
                     Saf, Sbf, sqf, Tq, cnt_g, survD, survI);
  hipLaunchKernelGGL(k2s_select, dim3(2048), dim3(256), 0, stream, survD, survI, cnt_g, idx48);
  hipLaunchKernelGGL(k2r_rerank, dim3(8192), dim3(256), 0, stream, f64d, sq64, idx48, idx40);
  hipLaunchKernelGGL(k1c_wfrag, dim3(48), dim3(256), 0, stream,
                     Wm1a, Wm1b, Wm2a, Wm2b, Wt1, Wp1, Wt2, Wp2,
                     F1a, F1b, F2a, F2b, Gu1, Gc1, Gu2, Gc2);
  hipLaunchKernelGGL(k1d_uc, dim3(128), dim3(256), 0, stream,
                     Saf, Gu1, Gc1, Gu2, Gc2, bt1, bp1, bt2, bp2, u1, c1, u2, c2);
  hipLaunchKernelGGL(k3_edgeconv, dim3(4096), dim3(256), 0, stream,
                     f32v, u1, c1, u2, c2, F1a, F1b, F2a, F2b,
                     bm1a, bm1b, bm2a, bm2b, idx40, hbuf);
  hipLaunchKernelGGL(k4_final, dim3(512), dim3(256), 0, stream, hbuf, WlT, bl, feature, out);
}